// Round 1
// baseline (1798.825 us; speedup 1.0000x reference)
//
#include <hip/hip_runtime.h>
#include <math.h>

// ---------------------------------------------------------------------------
// GAT 6-conv network, fp32. CSR-by-dst built on device each launch.
// ---------------------------------------------------------------------------

__global__ void k_deg(const int* __restrict__ dstv, int* __restrict__ deg, int E){
  int e = blockIdx.x*blockDim.x + threadIdx.x;
  if (e < E) atomicAdd(&deg[dstv[e]], 1);
}

// single-block exclusive scan of deg[N] -> off[N+1]; also cursor[i]=off[i]
__global__ void k_scan(const int* __restrict__ deg, int* __restrict__ off,
                       int* __restrict__ cursor, int N){
  __shared__ int sh[1024];
  __shared__ int carry_s;
  int t = threadIdx.x;
  if (t == 0) carry_s = 0;
  __syncthreads();
  for (int base = 0; base < N; base += 1024){
    int i = base + t;
    int v = (i < N) ? deg[i] : 0;
    sh[t] = v;
    __syncthreads();
    for (int d = 1; d < 1024; d <<= 1){
      int tmp = (t >= d) ? sh[t-d] : 0;
      __syncthreads();
      sh[t] += tmp;
      __syncthreads();
    }
    int inc = sh[t];
    int c = carry_s;
    if (i < N){ off[i+1] = c + inc; cursor[i] = c + inc - v; }
    __syncthreads();
    if (t == 1023) carry_s = c + sh[1023];
    __syncthreads();
  }
  if (t == 0) off[0] = 0;
}

__global__ void k_fill(const int* __restrict__ srcv, const int* __restrict__ dstv,
                       int* __restrict__ cursor, int* __restrict__ csr, int E){
  int e = blockIdx.x*blockDim.x + threadIdx.x;
  if (e < E){
    int d = dstv[e];
    int p = atomicAdd(&cursor[d], 1);
    csr[p] = srcv[e];
  }
}

// ---------------------------------------------------------------------------
// fp32 tiled GEMM: C[M,Nn] = A[M,K] @ B[K,Nn]. 64x64 tile, 4x4 per thread.
// ---------------------------------------------------------------------------
__global__ __launch_bounds__(256)
void gemm_f32(const float* __restrict__ A, const float* __restrict__ B,
              float* __restrict__ C, int M, int K, int Nn){
  __shared__ float As[16][65];
  __shared__ float Bs[16][64];
  int tid = threadIdx.x;
  int tx = tid & 15, ty = tid >> 4;
  int m0 = blockIdx.x * 64, n0 = blockIdx.y * 64;
  float acc[4][4] = {};
  for (int k0 = 0; k0 < K; k0 += 16){
    #pragma unroll
    for (int it = 0; it < 4; ++it){
      int idx = it*256 + tid;
      int mm = idx >> 4, kk = idx & 15;
      int gm = m0 + mm, gk = k0 + kk;
      As[kk][mm] = (gm < M && gk < K) ? A[(size_t)gm*K + gk] : 0.0f;
    }
    #pragma unroll
    for (int it = 0; it < 4; ++it){
      int idx = it*256 + tid;
      int kk = idx >> 6, nn = idx & 63;
      int gk = k0 + kk, gn = n0 + nn;
      Bs[kk][nn] = (gk < K && gn < Nn) ? B[(size_t)gk*Nn + gn] : 0.0f;
    }
    __syncthreads();
    #pragma unroll
    for (int kk = 0; kk < 16; ++kk){
      float a[4], b[4];
      #pragma unroll
      for (int i = 0; i < 4; ++i) a[i] = As[kk][ty*4+i];
      #pragma unroll
      for (int j = 0; j < 4; ++j) b[j] = Bs[kk][tx*4+j];
      #pragma unroll
      for (int i = 0; i < 4; ++i)
        #pragma unroll
        for (int j = 0; j < 4; ++j)
          acc[i][j] += a[i]*b[j];
    }
    __syncthreads();
  }
  #pragma unroll
  for (int i = 0; i < 4; ++i){
    int gm = m0 + ty*4 + i;
    if (gm >= M) continue;
    int gn = n0 + tx*4;
    if (gn + 3 < Nn){
      float4 v = make_float4(acc[i][0], acc[i][1], acc[i][2], acc[i][3]);
      *reinterpret_cast<float4*>(&C[(size_t)gm*Nn + gn]) = v;
    } else {
      #pragma unroll
      for (int j = 0; j < 4; ++j)
        if (gn + j < Nn) C[(size_t)gm*Nn + gn + j] = acc[i][j];
    }
  }
}

// ---------------------------------------------------------------------------
// per-node attention dots: als[n,h] = sum_c ht[n,h,c]*a_s[h,c]; same for ald.
// one wave per node (4 waves / block).
// ---------------------------------------------------------------------------
template<int HC>
__global__ void k_attn(const float* __restrict__ ht, const float* __restrict__ a_s,
                       const float* __restrict__ a_d, float* __restrict__ als,
                       float* __restrict__ ald, int N){
  int lane = threadIdx.x & 63;
  int wid  = threadIdx.x >> 6;
  int n = blockIdx.x*4 + wid;
  if (n >= N) return;
  if constexpr (HC == 8){
    if (lane < 8){
      float v = ht[(size_t)n*8 + lane];
      als[n*8+lane] = v * a_s[lane];
      ald[n*8+lane] = v * a_d[lane];
    }
  } else {
    constexpr int R = HC/64;
    float ps = 0.f, pd = 0.f;
    #pragma unroll
    for (int j = 0; j < R; ++j){
      int f = lane*R + j;
      float v = ht[(size_t)n*HC + f];
      ps += v * a_s[f];
      pd += v * a_d[f];
    }
    #pragma unroll
    for (int d = 1; d < 8; d <<= 1){
      ps += __shfl_xor(ps, d, 64);
      pd += __shfl_xor(pd, d, 64);
    }
    if ((lane & 7) == 0){
      als[n*8 + (lane>>3)] = ps;
      ald[n*8 + (lane>>3)] = pd;
    }
  }
}

// ---------------------------------------------------------------------------
// aggregation: per dst node segment-softmax over incoming edges (+self-loop),
// then out[n,:] = sum_e alpha[e,h] * ht[src_e,:], + bias, + activation.
// One wave per node. ACT: 0=none, 1=relu.
// ---------------------------------------------------------------------------
template<int HC, int ACT>
__global__ __launch_bounds__(256)
void k_agg(const float* __restrict__ ht, const float* __restrict__ als,
           const float* __restrict__ ald, const int* __restrict__ off,
           const int* __restrict__ csr, const float* __restrict__ bias,
           float* __restrict__ outb, int N){
  constexpr int R = HC/64;
  int lane = threadIdx.x & 63;
  int wid  = threadIdx.x >> 6;
  int n = blockIdx.x*4 + wid;
  if (n >= N) return;
  int o0 = off[n], deg = off[n+1]-o0;

  float aldn[8];
  #pragma unroll
  for (int h = 0; h < 8; ++h) aldn[h] = ald[n*8+h];

  // pass 1: per-head max over edges (incl. self-loop as virtual edge e==deg)
  float m[8];
  #pragma unroll
  for (int h = 0; h < 8; ++h) m[h] = -1e30f;
  for (int e = lane; e <= deg; e += 64){
    int src = (e < deg) ? csr[o0+e] : n;
    const float* ap = als + (size_t)src*8;
    #pragma unroll
    for (int h = 0; h < 8; ++h){
      float v = ap[h] + aldn[h];
      v = v > 0.0f ? v : 0.2f*v;
      m[h] = fmaxf(m[h], v);
    }
  }
  #pragma unroll
  for (int d = 1; d < 64; d <<= 1)
    #pragma unroll
    for (int h = 0; h < 8; ++h) m[h] = fmaxf(m[h], __shfl_xor(m[h], d, 64));

  // pass 2: per-head exp-sum
  float s[8] = {0,0,0,0,0,0,0,0};
  for (int e = lane; e <= deg; e += 64){
    int src = (e < deg) ? csr[o0+e] : n;
    const float* ap = als + (size_t)src*8;
    #pragma unroll
    for (int h = 0; h < 8; ++h){
      float v = ap[h] + aldn[h];
      v = v > 0.0f ? v : 0.2f*v;
      s[h] += __expf(v - m[h]);
    }
  }
  #pragma unroll
  for (int d = 1; d < 64; d <<= 1)
    #pragma unroll
    for (int h = 0; h < 8; ++h) s[h] += __shfl_xor(s[h], d, 64);

  int   myh = lane >> 3;
  float mh  = m[myh];
  float rsh = 1.0f/(s[myh] + 1e-16f);
  float adh = aldn[myh];

  float acc[R];
  #pragma unroll
  for (int j = 0; j < R; ++j) acc[j] = 0.0f;

  for (int e = 0; e <= deg; ++e){
    int src = (e < deg) ? csr[o0+e] : n;
    float v = als[(size_t)src*8 + myh] + adh;
    v = v > 0.0f ? v : 0.2f*v;
    float alpha = __expf(v - mh) * rsh;
    const float* hp = ht + (size_t)src*HC + lane*R;
    if constexpr (R == 1){
      acc[0] += alpha*hp[0];
    } else if constexpr (R == 4){
      float4 x = *reinterpret_cast<const float4*>(hp);
      acc[0]+=alpha*x.x; acc[1]+=alpha*x.y; acc[2]+=alpha*x.z; acc[3]+=alpha*x.w;
    } else {
      float4 x0 = *reinterpret_cast<const float4*>(hp);
      float4 x1 = *reinterpret_cast<const float4*>(hp+4);
      acc[0]+=alpha*x0.x; acc[1]+=alpha*x0.y; acc[2]+=alpha*x0.z; acc[3]+=alpha*x0.w;
      acc[4]+=alpha*x1.x; acc[5]+=alpha*x1.y; acc[6]+=alpha*x1.z; acc[7]+=alpha*x1.w;
    }
  }
  #pragma unroll
  for (int j = 0; j < R; ++j){
    int f = lane*R + j;
    float v = acc[j] + bias[f];
    if (ACT == 1) v = fmaxf(v, 0.0f);
    outb[(size_t)n*HC + f] = v;
  }
}

// ---------------------------------------------------------------------------
// BatchNorm (biased var) stats + apply(+leaky_relu 0.1)
// ---------------------------------------------------------------------------
__global__ void k_bn_stats(const float* __restrict__ x, float* __restrict__ gsum,
                           float* __restrict__ gsq, int N, int HC){
  int f = threadIdx.x;
  float s = 0.f, q = 0.f;
  for (int r = blockIdx.x; r < N; r += gridDim.x){
    float v = x[(size_t)r*HC + f];
    s += v; q += v*v;
  }
  atomicAdd(&gsum[f], s);
  atomicAdd(&gsq[f], q);
}

__global__ void k_bn_apply(float* __restrict__ x, const float* __restrict__ gsum,
                           const float* __restrict__ gsq, const float* __restrict__ g,
                           const float* __restrict__ b, int N, int HC){
  int i = blockIdx.x*blockDim.x + threadIdx.x;
  int total = N*HC;
  if (i >= total) return;
  int f = i % HC;
  float inv = 1.0f/(float)N;
  float mu  = gsum[f]*inv;
  float var = gsq[f]*inv - mu*mu;
  float v = (x[i]-mu)*rsqrtf(var+1e-5f)*g[f] + b[f];
  x[i] = v > 0.f ? v : 0.1f*v;
}

// ---------------------------------------------------------------------------
// final conv (512->1, 8 heads, concat=False): softmax, aggregate 8 features,
// mean over heads, +b, sigmoid. One thread per node.
// ---------------------------------------------------------------------------
__global__ void k_final(const float* __restrict__ ht8, const float* __restrict__ als,
                        const float* __restrict__ ald, const int* __restrict__ off,
                        const int* __restrict__ csr, const float* __restrict__ b32,
                        float* __restrict__ outp, int N){
  int n = blockIdx.x*blockDim.x + threadIdx.x;
  if (n >= N) return;
  int o0 = off[n], deg = off[n+1]-o0;
  float aldn[8], m[8], s[8], agg[8];
  #pragma unroll
  for (int h = 0; h < 8; ++h){ aldn[h] = ald[n*8+h]; m[h] = -1e30f; s[h]=0.f; agg[h]=0.f; }
  for (int e = 0; e <= deg; ++e){
    int src = (e < deg) ? csr[o0+e] : n;
    #pragma unroll
    for (int h = 0; h < 8; ++h){
      float v = als[(size_t)src*8+h] + aldn[h];
      v = v > 0.f ? v : 0.2f*v;
      m[h] = fmaxf(m[h], v);
    }
  }
  for (int e = 0; e <= deg; ++e){
    int src = (e < deg) ? csr[o0+e] : n;
    #pragma unroll
    for (int h = 0; h < 8; ++h){
      float v = als[(size_t)src*8+h] + aldn[h];
      v = v > 0.f ? v : 0.2f*v;
      float ex = __expf(v - m[h]);
      s[h] += ex;
      agg[h] += ex * ht8[(size_t)src*8+h];
    }
  }
  float o = 0.f;
  #pragma unroll
  for (int h = 0; h < 8; ++h) o += agg[h]/(s[h]+1e-16f);
  o = o*0.125f + b32[0];
  outp[n] = 1.0f/(1.0f + __expf(-o));
}

// ---------------------------------------------------------------------------
extern "C" void kernel_launch(void* const* d_in, const int* in_sizes, int n_in,
                              void* d_out, int out_size, void* d_ws, size_t ws_size,
                              hipStream_t stream){
  int N = in_sizes[0]/3;
  int E = in_sizes[1]/2;
  const float* x    = (const float*)d_in[0];
  const int*   ei   = (const int*)  d_in[1];
  const float* W11  = (const float*)d_in[2];
  const float* as11 = (const float*)d_in[3];
  const float* ad11 = (const float*)d_in[4];
  const float* b11  = (const float*)d_in[5];
  const float* W12  = (const float*)d_in[6];
  const float* as12 = (const float*)d_in[7];
  const float* ad12 = (const float*)d_in[8];
  const float* b12  = (const float*)d_in[9];
  const float* g1   = (const float*)d_in[10];
  const float* be1  = (const float*)d_in[11];
  const float* W21  = (const float*)d_in[12];
  const float* as21 = (const float*)d_in[13];
  const float* ad21 = (const float*)d_in[14];
  const float* b21  = (const float*)d_in[15];
  const float* W22  = (const float*)d_in[16];
  const float* as22 = (const float*)d_in[17];
  const float* ad22 = (const float*)d_in[18];
  const float* b22  = (const float*)d_in[19];
  const float* g2   = (const float*)d_in[20];
  const float* be2  = (const float*)d_in[21];
  const float* W31  = (const float*)d_in[22];
  const float* as31 = (const float*)d_in[23];
  const float* ad31 = (const float*)d_in[24];
  const float* b31  = (const float*)d_in[25];
  const float* W32  = (const float*)d_in[26];
  const float* as32 = (const float*)d_in[27];
  const float* ad32 = (const float*)d_in[28];
  const float* b32  = (const float*)d_in[29];

  char* ws = (char*)d_ws;
  size_t o = 0;
  auto alloc = [&](size_t bytes)->char*{
    char* p = ws + o;
    o = (o + bytes + 255) & ~(size_t)255;
    return p;
  };
  int*   deg    = (int*)  alloc((size_t)N*4);
  int*   off    = (int*)  alloc((size_t)(N+1)*4);
  int*   cursor = (int*)  alloc((size_t)N*4);
  int*   csr    = (int*)  alloc((size_t)E*4);
  float* als    = (float*)alloc((size_t)N*8*4);
  float* ald    = (float*)alloc((size_t)N*8*4);
  float* bsum   = (float*)alloc(256*4);
  float* bsq    = (float*)alloc(256*4);
  float* bufA   = (float*)alloc((size_t)N*512*4);
  float* bufB   = (float*)alloc((size_t)N*512*4);
  (void)ws_size;

  // ---- CSR build (by dst) ----
  hipMemsetAsync(deg, 0, (size_t)N*4, stream);
  int eb = (E+255)/256;
  k_deg <<<eb, 256, 0, stream>>>(ei+E, deg, E);
  k_scan<<<1, 1024, 0, stream>>>(deg, off, cursor, N);
  k_fill<<<eb, 256, 0, stream>>>(ei, ei+E, cursor, csr, E);

  auto gemm = [&](const float* A, const float* B, float* Cc, int M, int K, int Nn){
    dim3 g((M+63)/64, (Nn+63)/64);
    gemm_f32<<<g, 256, 0, stream>>>(A, B, Cc, M, K, Nn);
  };
  int nb4 = (N+3)/4;

  // ---- conv11: 3 -> 64, relu ----
  gemm(x, W11, bufB, N, 3, 64);
  k_attn<64><<<nb4,256,0,stream>>>(bufB, as11, ad11, als, ald, N);
  k_agg<64,1><<<nb4,256,0,stream>>>(bufB, als, ald, off, csr, b11, bufA, N);

  // ---- conv12: 64 -> 64, then BN + lrelu(0.1) ----
  gemm(bufA, W12, bufB, N, 64, 64);
  k_attn<64><<<nb4,256,0,stream>>>(bufB, as12, ad12, als, ald, N);
  k_agg<64,0><<<nb4,256,0,stream>>>(bufB, als, ald, off, csr, b12, bufA, N);
  hipMemsetAsync(bsum, 0, 64*4, stream);
  hipMemsetAsync(bsq,  0, 64*4, stream);
  k_bn_stats<<<512, 64, 0, stream>>>(bufA, bsum, bsq, N, 64);
  k_bn_apply<<<(N*64+255)/256, 256, 0, stream>>>(bufA, bsum, bsq, g1, be1, N, 64);

  // ---- conv21: 64 -> 256, relu ----
  gemm(bufA, W21, bufB, N, 64, 256);
  k_attn<256><<<nb4,256,0,stream>>>(bufB, as21, ad21, als, ald, N);
  k_agg<256,1><<<nb4,256,0,stream>>>(bufB, als, ald, off, csr, b21, bufA, N);

  // ---- conv22: 256 -> 256, then BN + lrelu(0.1) ----
  gemm(bufA, W22, bufB, N, 256, 256);
  k_attn<256><<<nb4,256,0,stream>>>(bufB, as22, ad22, als, ald, N);
  k_agg<256,0><<<nb4,256,0,stream>>>(bufB, als, ald, off, csr, b22, bufA, N);
  hipMemsetAsync(bsum, 0, 256*4, stream);
  hipMemsetAsync(bsq,  0, 256*4, stream);
  k_bn_stats<<<512, 256, 0, stream>>>(bufA, bsum, bsq, N, 256);
  k_bn_apply<<<(N*256+255)/256, 256, 0, stream>>>(bufA, bsum, bsq, g2, be2, N, 256);

  // ---- conv31: 256 -> 512, relu ----
  gemm(bufA, W31, bufB, N, 256, 512);
  k_attn<512><<<nb4,256,0,stream>>>(bufB, as31, ad31, als, ald, N);
  k_agg<512,1><<<nb4,256,0,stream>>>(bufB, als, ald, off, csr, b31, bufA, N);

  // ---- conv32: 512 -> 8 heads x 1, concat=False, mean, sigmoid ----
  gemm(bufA, W32, bufB, N, 512, 8);
  k_attn<8><<<nb4,256,0,stream>>>(bufB, as32, ad32, als, ald, N);
  k_final<<<(N+255)/256, 256, 0, stream>>>(bufB, als, ald, off, csr, b32,
                                           (float*)d_out, N);
}

// Round 2
// 1575.301 us; speedup vs baseline: 1.1419x; 1.1419x over previous
//
#include <hip/hip_runtime.h>
#include <math.h>

typedef short short8 __attribute__((ext_vector_type(8)));
typedef float f32x4 __attribute__((ext_vector_type(4)));

__device__ __forceinline__ unsigned short f2bf(float v){
  unsigned u = __builtin_bit_cast(unsigned, v);
  u += 0x7FFFu + ((u >> 16) & 1u);
  return (unsigned short)(u >> 16);
}
__device__ __forceinline__ float bf2f(unsigned short b){
  unsigned u = ((unsigned)b) << 16;
  return __builtin_bit_cast(float, u);
}

// ---------------------------------------------------------------------------
// CSR build (by dst)
// ---------------------------------------------------------------------------
__global__ void k_deg(const int* __restrict__ dstv, int* __restrict__ deg, int E){
  int e = blockIdx.x*blockDim.x + threadIdx.x;
  if (e < E) atomicAdd(&deg[dstv[e]], 1);
}

__global__ void k_scan(const int* __restrict__ deg, int* __restrict__ off,
                       int* __restrict__ cursor, int N){
  __shared__ int sh[1024];
  __shared__ int carry_s;
  int t = threadIdx.x;
  if (t == 0) carry_s = 0;
  __syncthreads();
  for (int base = 0; base < N; base += 1024){
    int i = base + t;
    int v = (i < N) ? deg[i] : 0;
    sh[t] = v;
    __syncthreads();
    for (int d = 1; d < 1024; d <<= 1){
      int tmp = (t >= d) ? sh[t-d] : 0;
      __syncthreads();
      sh[t] += tmp;
      __syncthreads();
    }
    int inc = sh[t];
    int c = carry_s;
    if (i < N){ off[i+1] = c + inc; cursor[i] = c + inc - v; }
    __syncthreads();
    if (t == 1023) carry_s = c + sh[1023];
    __syncthreads();
  }
  if (t == 0) off[0] = 0;
}

__global__ void k_fill(const int* __restrict__ srcv, const int* __restrict__ dstv,
                       int* __restrict__ cursor, int* __restrict__ csr, int E){
  int e = blockIdx.x*blockDim.x + threadIdx.x;
  if (e < E){
    int d = dstv[e];
    int p = atomicAdd(&cursor[d], 1);
    csr[p] = srcv[e];
  }
}

// ---------------------------------------------------------------------------
// B pre-convert: W fp32 [K, Nn] -> Bt_hi/Bt_lo bf16 [Nn][Kp] (transposed, padded)
// ---------------------------------------------------------------------------
__global__ void k_prepB(const float* __restrict__ W, unsigned short* __restrict__ bh,
                        unsigned short* __restrict__ bl, int K, int kpshift, int Nn){
  int Kp = 1 << kpshift;
  int i = blockIdx.x*blockDim.x + threadIdx.x;
  if (i >= Nn*Kp) return;
  int n = i >> kpshift, k = i & (Kp-1);
  float v = (k < K) ? W[(size_t)k*Nn + n] : 0.0f;
  unsigned short h = f2bf(v);
  bh[i] = h;
  bl[i] = f2bf(v - bf2f(h));
}

// ---------------------------------------------------------------------------
// bf16x3 MFMA GEMM. BM=64, BN = full output width (64/256/512).
// A fp32 [M,K] staged to LDS as bf16 hi/lo (XOR-swizzled). B from global bf16.
// Epilogue: store h (stride S=BN+16) + fused attention dots at cols BN..BN+15.
// ---------------------------------------------------------------------------
template<int BN>
__global__ __launch_bounds__((BN==64)?256:512)
void gemm_mfma(const float* __restrict__ A, const unsigned short* __restrict__ Bh,
               const unsigned short* __restrict__ Bl,
               const float* __restrict__ a_s, const float* __restrict__ a_d,
               float* __restrict__ P, int M, int K){
  constexpr int WAVES   = (BN==64) ? 4 : 8;
  constexpr int BLOCK   = WAVES*64;
  constexpr int WAVES_N = BN/64;          // 1,4,8
  constexpr int WAVES_M = WAVES/WAVES_N;  // 4,2,1
  constexpr int WM      = 64/WAVES_M;     // 16,32,64
  constexpr int MF      = WM/16;          // 1,2,4
  constexpr int CH      = (BN==512)?64 : (BN==256)?32 : 8;
  constexpr int S       = BN + 16;
  const int Kp = (K + 63) & ~(int)63;

  __shared__ char lds[16384];  // hi plane [64][64] bf16 @0, lo plane @8192

  int tid  = threadIdx.x;
  int lane = tid & 63;
  int wid  = tid >> 6;
  int wn = wid % WAVES_N;
  int wm = wid / WAVES_N;
  int n0w = wn*64;
  int wm0 = wm*WM;
  int m0 = blockIdx.x * 64;

  f32x4 acc[MF][4];
  #pragma unroll
  for (int i = 0; i < MF; ++i)
    #pragma unroll
    for (int j = 0; j < 4; ++j)
      acc[i][j] = (f32x4){0.f,0.f,0.f,0.f};

  constexpr int SITER = 512/BLOCK;

  for (int k0 = 0; k0 < Kp; k0 += 64){
    __syncthreads();
    #pragma unroll
    for (int it = 0; it < SITER; ++it){
      int i = it*BLOCK + tid;
      int row = i >> 3, c8 = i & 7;
      int gm = m0 + row;
      int gk = k0 + c8*8;
      float v[8];
      if (gm < M && gk + 8 <= K){
        const float* ap = A + (size_t)gm*K + gk;
        float4 x0 = *(const float4*)ap;
        float4 x1 = *(const float4*)(ap+4);
        v[0]=x0.x; v[1]=x0.y; v[2]=x0.z; v[3]=x0.w;
        v[4]=x1.x; v[5]=x1.y; v[6]=x1.z; v[7]=x1.w;
      } else {
        #pragma unroll
        for (int j=0;j<8;++j){
          int gkj = gk + j;
          v[j] = (gm < M && gkj < K) ? A[(size_t)gm*K + gkj] : 0.0f;
        }
      }
      short8 hi, lo;
      #pragma unroll
      for (int j=0;j<8;++j){
        unsigned short hb = f2bf(v[j]);
        hi[j] = (short)hb;
        lo[j] = (short)f2bf(v[j] - bf2f(hb));
      }
      int off = row*128 + ((c8 ^ (row&7))<<4);
      *(short8*)(lds + off) = hi;
      *(short8*)(lds + 8192 + off) = lo;
    }
    __syncthreads();
    #pragma unroll
    for (int kk = 0; kk < 2; ++kk){
      short8 bhf[4], blf[4];
      #pragma unroll
      for (int nf = 0; nf < 4; ++nf){
        int ncol = n0w + nf*16 + (lane & 15);
        int kidx = k0 + kk*32 + ((lane>>4)<<3);
        size_t bo = (size_t)ncol*Kp + kidx;
        bhf[nf] = *(const short8*)(Bh + bo);
        blf[nf] = *(const short8*)(Bl + bo);
      }
      #pragma unroll
      for (int mt = 0; mt < MF; ++mt){
        int row = wm0 + mt*16 + (lane & 15);
        int c8 = kk*4 + (lane>>4);
        int off = row*128 + ((c8 ^ (row&7))<<4);
        short8 ah = *(const short8*)(lds + off);
        short8 al = *(const short8*)(lds + 8192 + off);
        #pragma unroll
        for (int nf = 0; nf < 4; ++nf){
          acc[mt][nf] = __builtin_amdgcn_mfma_f32_16x16x32_bf16(ah, bhf[nf], acc[mt][nf], 0,0,0);
          acc[mt][nf] = __builtin_amdgcn_mfma_f32_16x16x32_bf16(ah, blf[nf], acc[mt][nf], 0,0,0);
          acc[mt][nf] = __builtin_amdgcn_mfma_f32_16x16x32_bf16(al, bhf[nf], acc[mt][nf], 0,0,0);
        }
      }
    }
  }

  // ---- epilogue: store h + fused attention dots ----
  float asv[4], adv[4];
  #pragma unroll
  for (int nf=0; nf<4; ++nf){
    int gcol = n0w + nf*16 + (lane&15);
    asv[nf] = a_s[gcol];
    adv[nf] = a_d[gcol];
  }
  #pragma unroll
  for (int mt = 0; mt < MF; ++mt){
    #pragma unroll
    for (int r = 0; r < 4; ++r){
      int gm = m0 + wm0 + mt*16 + ((lane>>4)<<2) + r;
      bool ok = gm < M;
      float* rowp = P + (size_t)gm*S;
      #pragma unroll
      for (int nf=0;nf<4;++nf){
        if (ok) rowp[n0w + nf*16 + (lane&15)] = acc[mt][nf][r];
      }
      if constexpr (CH == 64){
        float ps = acc[mt][0][r]*asv[0] + acc[mt][1][r]*asv[1]
                 + acc[mt][2][r]*asv[2] + acc[mt][3][r]*asv[3];
        float pd = acc[mt][0][r]*adv[0] + acc[mt][1][r]*adv[1]
                 + acc[mt][2][r]*adv[2] + acc[mt][3][r]*adv[3];
        #pragma unroll
        for (int d2=1; d2<16; d2<<=1){ ps += __shfl_xor(ps,d2,64); pd += __shfl_xor(pd,d2,64); }
        if (ok && (lane&15)==0){
          int head = n0w >> 6;
          rowp[BN + head] = ps;
          rowp[BN + 8 + head] = pd;
        }
      } else if constexpr (CH == 32){
        float ps0 = acc[mt][0][r]*asv[0] + acc[mt][1][r]*asv[1];
        float ps1 = acc[mt][2][r]*asv[2] + acc[mt][3][r]*asv[3];
        float pd0 = acc[mt][0][r]*adv[0] + acc[mt][1][r]*adv[1];
        float pd1 = acc[mt][2][r]*adv[2] + acc[mt][3][r]*adv[3];
        #pragma unroll
        for (int d2=1; d2<16; d2<<=1){
          ps0 += __shfl_xor(ps0,d2,64); ps1 += __shfl_xor(ps1,d2,64);
          pd0 += __shfl_xor(pd0,d2,64); pd1 += __shfl_xor(pd1,d2,64);
        }
        if (ok && (lane&15)==0){
          int head = n0w >> 5;
          rowp[BN + head]     = ps0;
          rowp[BN + head + 1] = ps1;
          rowp[BN + 8 + head]     = pd0;
          rowp[BN + 8 + head + 1] = pd1;
        }
      } else { // CH == 8
        #pragma unroll
        for (int nf=0;nf<4;++nf){
          float ps = acc[mt][nf][r]*asv[nf];
          float pd = acc[mt][nf][r]*adv[nf];
          #pragma unroll
          for (int d2=1; d2<8; d2<<=1){ ps += __shfl_xor(ps,d2,64); pd += __shfl_xor(pd,d2,64); }
          if (ok && (lane&7)==0){
            int head = nf*2 + ((lane>>3)&1);
            rowp[BN + head]     = ps;
            rowp[BN + 8 + head] = pd;
          }
        }
      }
    }
  }
}

// ---------------------------------------------------------------------------
// fp32 tiled GEMM (kept for conv32: N=8, K=512)
// ---------------------------------------------------------------------------
__global__ __launch_bounds__(256)
void gemm_f32(const float* __restrict__ A, const float* __restrict__ B,
              float* __restrict__ C, int M, int K, int Nn){
  __shared__ float As[16][65];
  __shared__ float Bs[16][64];
  int tid = threadIdx.x;
  int tx = tid & 15, ty = tid >> 4;
  int m0 = blockIdx.x * 64, n0 = blockIdx.y * 64;
  float acc[4][4] = {};
  for (int k0 = 0; k0 < K; k0 += 16){
    #pragma unroll
    for (int it = 0; it < 4; ++it){
      int idx = it*256 + tid;
      int mm = idx >> 4, kk = idx & 15;
      int gm = m0 + mm, gk = k0 + kk;
      As[kk][mm] = (gm < M && gk < K) ? A[(size_t)gm*K + gk] : 0.0f;
    }
    #pragma unroll
    for (int it = 0; it < 4; ++it){
      int idx = it*256 + tid;
      int kk = idx >> 6, nn = idx & 63;
      int gk = k0 + kk, gn = n0 + nn;
      Bs[kk][nn] = (gk < K && gn < Nn) ? B[(size_t)gk*Nn + gn] : 0.0f;
    }
    __syncthreads();
    #pragma unroll
    for (int kk = 0; kk < 16; ++kk){
      float a[4], b[4];
      #pragma unroll
      for (int i = 0; i < 4; ++i) a[i] = As[kk][ty*4+i];
      #pragma unroll
      for (int j = 0; j < 4; ++j) b[j] = Bs[kk][tx*4+j];
      #pragma unroll
      for (int i = 0; i < 4; ++i)
        #pragma unroll
        for (int j = 0; j < 4; ++j)
          acc[i][j] += a[i]*b[j];
    }
    __syncthreads();
  }
  #pragma unroll
  for (int i = 0; i < 4; ++i){
    int gm = m0 + ty*4 + i;
    if (gm >= M) continue;
    int gn = n0 + tx*4;
    #pragma unroll
    for (int j = 0; j < 4; ++j)
      if (gn + j < Nn) C[(size_t)gm*Nn + gn + j] = acc[i][j];
  }
}

// attention dots for the final conv (HC=8, C=1)
__global__ void k_attn8(const float* __restrict__ ht, const float* __restrict__ a_s,
                        const float* __restrict__ a_d, float* __restrict__ als,
                        float* __restrict__ ald, int N){
  int i = blockIdx.x*blockDim.x + threadIdx.x;
  if (i >= N*8) return;
  int h = i & 7;
  float v = ht[i];
  als[i] = v * a_s[h];
  ald[i] = v * a_d[h];
}

// ---------------------------------------------------------------------------
// aggregation with interleaved dots: ht rows have stride SIN=HC+16,
// als at col HC+h, ald at col HC+8+h. Output dense stride HC.
// ---------------------------------------------------------------------------
template<int HC, int ACT>
__global__ __launch_bounds__(256)
void k_agg(const float* __restrict__ ht, const int* __restrict__ off,
           const int* __restrict__ csr, const float* __restrict__ bias,
           float* __restrict__ outb, int N){
  constexpr int SIN = HC + 16;
  constexpr int R = HC/64;
  int lane = threadIdx.x & 63;
  int wid  = threadIdx.x >> 6;
  int n = blockIdx.x*4 + wid;
  if (n >= N) return;
  int o0 = off[n], deg = off[n+1]-o0;

  float aldn[8];
  #pragma unroll
  for (int h = 0; h < 8; ++h) aldn[h] = ht[(size_t)n*SIN + HC + 8 + h];

  float m[8];
  #pragma unroll
  for (int h = 0; h < 8; ++h) m[h] = -1e30f;
  for (int e = lane; e <= deg; e += 64){
    int src = (e < deg) ? csr[o0+e] : n;
    const float* ap = ht + (size_t)src*SIN + HC;
    #pragma unroll
    for (int h = 0; h < 8; ++h){
      float v = ap[h] + aldn[h];
      v = v > 0.0f ? v : 0.2f*v;
      m[h] = fmaxf(m[h], v);
    }
  }
  #pragma unroll
  for (int d = 1; d < 64; d <<= 1)
    #pragma unroll
    for (int h = 0; h < 8; ++h) m[h] = fmaxf(m[h], __shfl_xor(m[h], d, 64));

  float s[8] = {0,0,0,0,0,0,0,0};
  for (int e = lane; e <= deg; e += 64){
    int src = (e < deg) ? csr[o0+e] : n;
    const float* ap = ht + (size_t)src*SIN + HC;
    #pragma unroll
    for (int h = 0; h < 8; ++h){
      float v = ap[h] + aldn[h];
      v = v > 0.0f ? v : 0.2f*v;
      s[h] += __expf(v - m[h]);
    }
  }
  #pragma unroll
  for (int d = 1; d < 64; d <<= 1)
    #pragma unroll
    for (int h = 0; h < 8; ++h) s[h] += __shfl_xor(s[h], d, 64);

  int   myh = lane >> 3;
  float mh  = m[myh];
  float rsh = 1.0f/(s[myh] + 1e-16f);
  float adh = aldn[myh];

  float acc[R];
  #pragma unroll
  for (int j = 0; j < R; ++j) acc[j] = 0.0f;

  for (int e = 0; e <= deg; ++e){
    int src = (e < deg) ? csr[o0+e] : n;
    float v = ht[(size_t)src*SIN + HC + myh] + adh;
    v = v > 0.0f ? v : 0.2f*v;
    float alpha = __expf(v - mh) * rsh;
    const float* hp = ht + (size_t)src*SIN + lane*R;
    if constexpr (R == 1){
      acc[0] += alpha*hp[0];
    } else if constexpr (R == 4){
      float4 x = *reinterpret_cast<const float4*>(hp);
      acc[0]+=alpha*x.x; acc[1]+=alpha*x.y; acc[2]+=alpha*x.z; acc[3]+=alpha*x.w;
    } else {
      float4 x0 = *reinterpret_cast<const float4*>(hp);
      float4 x1 = *reinterpret_cast<const float4*>(hp+4);
      acc[0]+=alpha*x0.x; acc[1]+=alpha*x0.y; acc[2]+=alpha*x0.z; acc[3]+=alpha*x0.w;
      acc[4]+=alpha*x1.x; acc[5]+=alpha*x1.y; acc[6]+=alpha*x1.z; acc[7]+=alpha*x1.w;
    }
  }
  #pragma unroll
  for (int j = 0; j < R; ++j){
    int f = lane*R + j;
    float v = acc[j] + bias[f];
    if (ACT == 1) v = fmaxf(v, 0.0f);
    outb[(size_t)n*HC + f] = v;
  }
}

// ---------------------------------------------------------------------------
// BatchNorm stats + apply(+leaky_relu 0.1), dense stride HC
// ---------------------------------------------------------------------------
__global__ void k_bn_stats(const float* __restrict__ x, float* __restrict__ gsum,
                           float* __restrict__ gsq, int N, int HC){
  int f = threadIdx.x;
  float s = 0.f, q = 0.f;
  for (int r = blockIdx.x; r < N; r += gridDim.x){
    float v = x[(size_t)r*HC + f];
    s += v; q += v*v;
  }
  atomicAdd(&gsum[f], s);
  atomicAdd(&gsq[f], q);
}

__global__ void k_bn_apply(float* __restrict__ x, const float* __restrict__ gsum,
                           const float* __restrict__ gsq, const float* __restrict__ g,
                           const float* __restrict__ b, int N, int HC){
  int i = blockIdx.x*blockDim.x + threadIdx.x;
  int total = N*HC;
  if (i >= total) return;
  int f = i % HC;
  float inv = 1.0f/(float)N;
  float mu  = gsum[f]*inv;
  float var = gsq[f]*inv - mu*mu;
  float v = (x[i]-mu)*rsqrtf(var+1e-5f)*g[f] + b[f];
  x[i] = v > 0.f ? v : 0.1f*v;
}

// ---------------------------------------------------------------------------
// final conv (512->1, 8 heads, mean, sigmoid)
// ---------------------------------------------------------------------------
__global__ void k_final(const float* __restrict__ ht8, const float* __restrict__ als,
                        const float* __restrict__ ald, const int* __restrict__ off,
                        const int* __restrict__ csr, const float* __restrict__ b32,
                        float* __restrict__ outp, int N){
  int n = blockIdx.x*blockDim.x + threadIdx.x;
  if (n >= N) return;
  int o0 = off[n], deg = off[n+1]-o0;
  float aldn[8], m[8], s[8], agg[8];
  #pragma unroll
  for (int h = 0; h < 8; ++h){ aldn[h] = ald[n*8+h]; m[h] = -1e30f; s[h]=0.f; agg[h]=0.f; }
  for (int e = 0; e <= deg; ++e){
    int src = (e < deg) ? csr[o0+e] : n;
    #pragma unroll
    for (int h = 0; h < 8; ++h){
      float v = als[(size_t)src*8+h] + aldn[h];
      v = v > 0.f ? v : 0.2f*v;
      m[h] = fmaxf(m[h], v);
    }
  }
  for (int e = 0; e <= deg; ++e){
    int src = (e < deg) ? csr[o0+e] : n;
    #pragma unroll
    for (int h = 0; h < 8; ++h){
      float v = als[(size_t)src*8+h] + aldn[h];
      v = v > 0.f ? v : 0.2f*v;
      float ex = __expf(v - m[h]);
      s[h] += ex;
      agg[h] += ex * ht8[(size_t)src*8+h];
    }
  }
  float o = 0.f;
  #pragma unroll
  for (int h = 0; h < 8; ++h) o += agg[h]/(s[h]+1e-16f);
  o = o*0.125f + b32[0];
  outp[n] = 1.0f/(1.0f + __expf(-o));
}

// ---------------------------------------------------------------------------
extern "C" void kernel_launch(void* const* d_in, const int* in_sizes, int n_in,
                              void* d_out, int out_size, void* d_ws, size_t ws_size,
                              hipStream_t stream){
  int N = in_sizes[0]/3;
  int E = in_sizes[1]/2;
  const float* x    = (const float*)d_in[0];
  const int*   ei   = (const int*)  d_in[1];
  const float* W11  = (const float*)d_in[2];
  const float* as11 = (const float*)d_in[3];
  const float* ad11 = (const float*)d_in[4];
  const float* b11  = (const float*)d_in[5];
  const float* W12  = (const float*)d_in[6];
  const float* as12 = (const float*)d_in[7];
  const float* ad12 = (const float*)d_in[8];
  const float* b12  = (const float*)d_in[9];
  const float* g1   = (const float*)d_in[10];
  const float* be1  = (const float*)d_in[11];
  const float* W21  = (const float*)d_in[12];
  const float* as21 = (const float*)d_in[13];
  const float* ad21 = (const float*)d_in[14];
  const float* b21  = (const float*)d_in[15];
  const float* W22  = (const float*)d_in[16];
  const float* as22 = (const float*)d_in[17];
  const float* ad22 = (const float*)d_in[18];
  const float* b22  = (const float*)d_in[19];
  const float* g2   = (const float*)d_in[20];
  const float* be2  = (const float*)d_in[21];
  const float* W31  = (const float*)d_in[22];
  const float* as31 = (const float*)d_in[23];
  const float* ad31 = (const float*)d_in[24];
  const float* b31  = (const float*)d_in[25];
  const float* W32  = (const float*)d_in[26];
  const float* as32 = (const float*)d_in[27];
  const float* ad32 = (const float*)d_in[28];
  const float* b32  = (const float*)d_in[29];

  char* ws = (char*)d_ws;
  size_t o = 0;
  auto alloc = [&](size_t bytes)->char*{
    char* p = ws + o;
    o = (o + bytes + 255) & ~(size_t)255;
    return p;
  };
  int*   deg    = (int*)  alloc((size_t)N*4);
  int*   off    = (int*)  alloc((size_t)(N+1)*4);
  int*   cursor = (int*)  alloc((size_t)N*4);
  int*   csr    = (int*)  alloc((size_t)E*4);
  unsigned short* bth = (unsigned short*)alloc(131072*2);
  unsigned short* btl = (unsigned short*)alloc(131072*2);
  float* als8   = (float*)alloc((size_t)N*8*4);
  float* ald8   = (float*)alloc((size_t)N*8*4);
  float* h8     = (float*)alloc((size_t)N*8*4);
  float* bsum   = (float*)alloc(256*4);
  float* bsq    = (float*)alloc(256*4);
  float* P      = (float*)alloc((size_t)N*528*4);  // pre-agg (h + dots), stride HC+16
  float* Q      = (float*)alloc((size_t)N*512*4);  // post-agg, dense
  (void)ws_size;

  // ---- CSR build ----
  hipMemsetAsync(deg, 0, (size_t)N*4, stream);
  int eb = (E+255)/256;
  k_deg <<<eb, 256, 0, stream>>>(ei+E, deg, E);
  k_scan<<<1, 1024, 0, stream>>>(deg, off, cursor, N);
  k_fill<<<eb, 256, 0, stream>>>(ei, ei+E, cursor, csr, E);

  int mb = (N+63)/64;
  int nb4 = (N+3)/4;

  // ---- conv11: 3 -> 64 (Kp=64), relu ----
  k_prepB<<<(64*64)/256, 256, 0, stream>>>(W11, bth, btl, 3, 6, 64);
  gemm_mfma<64><<<mb, 256, 0, stream>>>(x, bth, btl, as11, ad11, P, N, 3);
  k_agg<64,1><<<nb4, 256, 0, stream>>>(P, off, csr, b11, Q, N);

  // ---- conv12: 64 -> 64, BN + lrelu(0.1) ----
  k_prepB<<<(64*64)/256, 256, 0, stream>>>(W12, bth, btl, 64, 6, 64);
  gemm_mfma<64><<<mb, 256, 0, stream>>>(Q, bth, btl, as12, ad12, P, N, 64);
  k_agg<64,0><<<nb4, 256, 0, stream>>>(P, off, csr, b12, Q, N);
  hipMemsetAsync(bsum, 0, 64*4, stream);
  hipMemsetAsync(bsq,  0, 64*4, stream);
  k_bn_stats<<<512, 64, 0, stream>>>(Q, bsum, bsq, N, 64);
  k_bn_apply<<<(N*64+255)/256, 256, 0, stream>>>(Q, bsum, bsq, g1, be1, N, 64);

  // ---- conv21: 64 -> 256, relu ----
  k_prepB<<<(256*64)/256, 256, 0, stream>>>(W21, bth, btl, 64, 6, 256);
  gemm_mfma<256><<<mb, 512, 0, stream>>>(Q, bth, btl, as21, ad21, P, N, 64);
  k_agg<256,1><<<nb4, 256, 0, stream>>>(P, off, csr, b21, Q, N);

  // ---- conv22: 256 -> 256, BN + lrelu(0.1) ----
  k_prepB<<<(256*256)/256, 256, 0, stream>>>(W22, bth, btl, 256, 8, 256);
  gemm_mfma<256><<<mb, 512, 0, stream>>>(Q, bth, btl, as22, ad22, P, N, 256);
  k_agg<256,0><<<nb4, 256, 0, stream>>>(P, off, csr, b22, Q, N);
  hipMemsetAsync(bsum, 0, 256*4, stream);
  hipMemsetAsync(bsq,  0, 256*4, stream);
  k_bn_stats<<<512, 256, 0, stream>>>(Q, bsum, bsq, N, 256);
  k_bn_apply<<<(N*256+255)/256, 256, 0, stream>>>(Q, bsum, bsq, g2, be2, N, 256);

  // ---- conv31: 256 -> 512, relu ----
  k_prepB<<<(512*256)/256, 256, 0, stream>>>(W31, bth, btl, 256, 8, 512);
  gemm_mfma<512><<<mb, 512, 0, stream>>>(Q, bth, btl, as31, ad31, P, N, 256);
  k_agg<512,1><<<nb4, 256, 0, stream>>>(P, off, csr, b31, Q, N);

  // ---- conv32: 512 -> 8x1, concat=False, mean, sigmoid ----
  {
    dim3 g((N+63)/64, 1);
    gemm_f32<<<g, 256, 0, stream>>>(Q, W32, h8, N, 512, 8);
  }
  k_attn8<<<(N*8+255)/256, 256, 0, stream>>>(h8, as32, ad32, als8, ald8, N);
  k_final<<<(N+255)/256, 256, 0, stream>>>(h8, als8, ald8, off, csr, b32,
                                           (float*)d_out, N);
}

// Round 3
// 1251.003 us; speedup vs baseline: 1.4379x; 1.2592x over previous
//
#include <hip/hip_runtime.h>
#include <math.h>

typedef short short8 __attribute__((ext_vector_type(8)));
typedef short short4v __attribute__((ext_vector_type(4)));
typedef float f32x4 __attribute__((ext_vector_type(4)));

__device__ __forceinline__ unsigned short f2bf(float v){
  unsigned u = __builtin_bit_cast(unsigned, v);
  u += 0x7FFFu + ((u >> 16) & 1u);
  return (unsigned short)(u >> 16);
}
__device__ __forceinline__ float bf2f(unsigned short b){
  unsigned u = ((unsigned)b) << 16;
  return __builtin_bit_cast(float, u);
}

// ---------------------------------------------------------------------------
// CSR build (by dst)
// ---------------------------------------------------------------------------
__global__ void k_deg(const int* __restrict__ dstv, int* __restrict__ deg, int E){
  int e = blockIdx.x*blockDim.x + threadIdx.x;
  if (e < E) atomicAdd(&deg[dstv[e]], 1);
}

__global__ void k_scan(const int* __restrict__ deg, int* __restrict__ off,
                       int* __restrict__ cursor, int N){
  __shared__ int sh[1024];
  __shared__ int carry_s;
  int t = threadIdx.x;
  if (t == 0) carry_s = 0;
  __syncthreads();
  for (int base = 0; base < N; base += 1024){
    int i = base + t;
    int v = (i < N) ? deg[i] : 0;
    sh[t] = v;
    __syncthreads();
    for (int d = 1; d < 1024; d <<= 1){
      int tmp = (t >= d) ? sh[t-d] : 0;
      __syncthreads();
      sh[t] += tmp;
      __syncthreads();
    }
    int inc = sh[t];
    int c = carry_s;
    if (i < N){ off[i+1] = c + inc; cursor[i] = c + inc - v; }
    __syncthreads();
    if (t == 1023) carry_s = c + sh[1023];
    __syncthreads();
  }
  if (t == 0) off[0] = 0;
}

__global__ void k_fill(const int* __restrict__ srcv, const int* __restrict__ dstv,
                       int* __restrict__ cursor, int* __restrict__ csr, int E){
  int e = blockIdx.x*blockDim.x + threadIdx.x;
  if (e < E){
    int d = dstv[e];
    int p = atomicAdd(&cursor[d], 1);
    csr[p] = srcv[e];
  }
}

// ---------------------------------------------------------------------------
// B pre-convert: W fp32 [K, Nn] -> Bt_hi/Bt_lo bf16 [Nn][Kp]
// ---------------------------------------------------------------------------
__global__ void k_prepB(const float* __restrict__ W, unsigned short* __restrict__ bh,
                        unsigned short* __restrict__ bl, int K, int kpshift, int Nn){
  int Kp = 1 << kpshift;
  int i = blockIdx.x*blockDim.x + threadIdx.x;
  if (i >= Nn*Kp) return;
  int n = i >> kpshift, k = i & (Kp-1);
  float v = (k < K) ? W[(size_t)k*Nn + n] : 0.0f;
  unsigned short h = f2bf(v);
  bh[i] = h;
  bl[i] = f2bf(v - bf2f(h));
}

// ---------------------------------------------------------------------------
// bf16x3 MFMA GEMM. BM=64, BN = full width. Epilogue: h -> bf16 Pb (stride BN),
// fused attention dots -> fp32 D (stride 16: [0..7]=als, [8..15]=ald).
// ---------------------------------------------------------------------------
template<int BN>
__global__ __launch_bounds__((BN==64)?256:512)
void gemm_mfma(const float* __restrict__ A, const unsigned short* __restrict__ Bh,
               const unsigned short* __restrict__ Bl,
               const float* __restrict__ a_s, const float* __restrict__ a_d,
               unsigned short* __restrict__ Pb, float* __restrict__ D, int M, int K){
  constexpr int WAVES   = (BN==64) ? 4 : 8;
  constexpr int BLOCK   = WAVES*64;
  constexpr int WAVES_N = BN/64;
  constexpr int WAVES_M = WAVES/WAVES_N;
  constexpr int WM      = 64/WAVES_M;
  constexpr int MF      = WM/16;
  constexpr int CH      = (BN==512)?64 : (BN==256)?32 : 8;
  const int Kp = (K + 63) & ~(int)63;

  __shared__ char lds[16384];

  int tid  = threadIdx.x;
  int lane = tid & 63;
  int wid  = tid >> 6;
  int wn = wid % WAVES_N;
  int wm = wid / WAVES_N;
  int n0w = wn*64;
  int wm0 = wm*WM;
  int m0 = blockIdx.x * 64;

  f32x4 acc[MF][4];
  #pragma unroll
  for (int i = 0; i < MF; ++i)
    #pragma unroll
    for (int j = 0; j < 4; ++j)
      acc[i][j] = (f32x4){0.f,0.f,0.f,0.f};

  constexpr int SITER = 512/BLOCK;

  for (int k0 = 0; k0 < Kp; k0 += 64){
    __syncthreads();
    #pragma unroll
    for (int it = 0; it < SITER; ++it){
      int i = it*BLOCK + tid;
      int row = i >> 3, c8 = i & 7;
      int gm = m0 + row;
      int gk = k0 + c8*8;
      float v[8];
      if (gm < M && gk + 8 <= K){
        const float* ap = A + (size_t)gm*K + gk;
        float4 x0 = *(const float4*)ap;
        float4 x1 = *(const float4*)(ap+4);
        v[0]=x0.x; v[1]=x0.y; v[2]=x0.z; v[3]=x0.w;
        v[4]=x1.x; v[5]=x1.y; v[6]=x1.z; v[7]=x1.w;
      } else {
        #pragma unroll
        for (int j=0;j<8;++j){
          int gkj = gk + j;
          v[j] = (gm < M && gkj < K) ? A[(size_t)gm*K + gkj] : 0.0f;
        }
      }
      short8 hi, lo;
      #pragma unroll
      for (int j=0;j<8;++j){
        unsigned short hb = f2bf(v[j]);
        hi[j] = (short)hb;
        lo[j] = (short)f2bf(v[j] - bf2f(hb));
      }
      int off = row*128 + ((c8 ^ (row&7))<<4);
      *(short8*)(lds + off) = hi;
      *(short8*)(lds + 8192 + off) = lo;
    }
    __syncthreads();
    #pragma unroll
    for (int kk = 0; kk < 2; ++kk){
      short8 bhf[4], blf[4];
      #pragma unroll
      for (int nf = 0; nf < 4; ++nf){
        int ncol = n0w + nf*16 + (lane & 15);
        int kidx = k0 + kk*32 + ((lane>>4)<<3);
        size_t bo = (size_t)ncol*Kp + kidx;
        bhf[nf] = *(const short8*)(Bh + bo);
        blf[nf] = *(const short8*)(Bl + bo);
      }
      #pragma unroll
      for (int mt = 0; mt < MF; ++mt){
        int row = wm0 + mt*16 + (lane & 15);
        int c8 = kk*4 + (lane>>4);
        int off = row*128 + ((c8 ^ (row&7))<<4);
        short8 ah = *(const short8*)(lds + off);
        short8 al = *(const short8*)(lds + 8192 + off);
        #pragma unroll
        for (int nf = 0; nf < 4; ++nf){
          acc[mt][nf] = __builtin_amdgcn_mfma_f32_16x16x32_bf16(ah, bhf[nf], acc[mt][nf], 0,0,0);
          acc[mt][nf] = __builtin_amdgcn_mfma_f32_16x16x32_bf16(ah, blf[nf], acc[mt][nf], 0,0,0);
          acc[mt][nf] = __builtin_amdgcn_mfma_f32_16x16x32_bf16(al, bhf[nf], acc[mt][nf], 0,0,0);
        }
      }
    }
  }

  float asv[4], adv[4];
  #pragma unroll
  for (int nf=0; nf<4; ++nf){
    int gcol = n0w + nf*16 + (lane&15);
    asv[nf] = a_s[gcol];
    adv[nf] = a_d[gcol];
  }
  #pragma unroll
  for (int mt = 0; mt < MF; ++mt){
    #pragma unroll
    for (int r = 0; r < 4; ++r){
      int gm = m0 + wm0 + mt*16 + ((lane>>4)<<2) + r;
      bool ok = gm < M;
      #pragma unroll
      for (int nf=0;nf<4;++nf){
        if (ok) Pb[(size_t)gm*BN + n0w + nf*16 + (lane&15)] = f2bf(acc[mt][nf][r]);
      }
      float* dp = D + (size_t)gm*16;
      if constexpr (CH == 64){
        float ps = acc[mt][0][r]*asv[0] + acc[mt][1][r]*asv[1]
                 + acc[mt][2][r]*asv[2] + acc[mt][3][r]*asv[3];
        float pd = acc[mt][0][r]*adv[0] + acc[mt][1][r]*adv[1]
                 + acc[mt][2][r]*adv[2] + acc[mt][3][r]*adv[3];
        #pragma unroll
        for (int d2=1; d2<16; d2<<=1){ ps += __shfl_xor(ps,d2,64); pd += __shfl_xor(pd,d2,64); }
        if (ok && (lane&15)==0){
          int head = n0w >> 6;
          dp[head] = ps;
          dp[8 + head] = pd;
        }
      } else if constexpr (CH == 32){
        float ps0 = acc[mt][0][r]*asv[0] + acc[mt][1][r]*asv[1];
        float ps1 = acc[mt][2][r]*asv[2] + acc[mt][3][r]*asv[3];
        float pd0 = acc[mt][0][r]*adv[0] + acc[mt][1][r]*adv[1];
        float pd1 = acc[mt][2][r]*adv[2] + acc[mt][3][r]*adv[3];
        #pragma unroll
        for (int d2=1; d2<16; d2<<=1){
          ps0 += __shfl_xor(ps0,d2,64); ps1 += __shfl_xor(ps1,d2,64);
          pd0 += __shfl_xor(pd0,d2,64); pd1 += __shfl_xor(pd1,d2,64);
        }
        if (ok && (lane&15)==0){
          int head = n0w >> 5;
          dp[head]     = ps0;
          dp[head + 1] = ps1;
          dp[8 + head]     = pd0;
          dp[8 + head + 1] = pd1;
        }
      } else {
        #pragma unroll
        for (int nf=0;nf<4;++nf){
          float ps = acc[mt][nf][r]*asv[nf];
          float pd = acc[mt][nf][r]*adv[nf];
          #pragma unroll
          for (int d2=1; d2<8; d2<<=1){ ps += __shfl_xor(ps,d2,64); pd += __shfl_xor(pd,d2,64); }
          if (ok && (lane&7)==0){
            int head = nf*2 + ((lane>>3)&1);
            dp[head]     = ps;
            dp[8 + head] = pd;
          }
        }
      }
    }
  }
}

// ---------------------------------------------------------------------------
// fp32 tiled GEMM (conv32: N=8, K=512)
// ---------------------------------------------------------------------------
__global__ __launch_bounds__(256)
void gemm_f32(const float* __restrict__ A, const float* __restrict__ B,
              float* __restrict__ C, int M, int K, int Nn){
  __shared__ float As[16][65];
  __shared__ float Bs[16][64];
  int tid = threadIdx.x;
  int tx = tid & 15, ty = tid >> 4;
  int m0 = blockIdx.x * 64, n0 = blockIdx.y * 64;
  float acc[4][4] = {};
  for (int k0 = 0; k0 < K; k0 += 16){
    #pragma unroll
    for (int it = 0; it < 4; ++it){
      int idx = it*256 + tid;
      int mm = idx >> 4, kk = idx & 15;
      int gm = m0 + mm, gk = k0 + kk;
      As[kk][mm] = (gm < M && gk < K) ? A[(size_t)gm*K + gk] : 0.0f;
    }
    #pragma unroll
    for (int it = 0; it < 4; ++it){
      int idx = it*256 + tid;
      int kk = idx >> 6, nn = idx & 63;
      int gk = k0 + kk, gn = n0 + nn;
      Bs[kk][nn] = (gk < K && gn < Nn) ? B[(size_t)gk*Nn + gn] : 0.0f;
    }
    __syncthreads();
    #pragma unroll
    for (int kk = 0; kk < 16; ++kk){
      float a[4], b[4];
      #pragma unroll
      for (int i = 0; i < 4; ++i) a[i] = As[kk][ty*4+i];
      #pragma unroll
      for (int j = 0; j < 4; ++j) b[j] = Bs[kk][tx*4+j];
      #pragma unroll
      for (int i = 0; i < 4; ++i)
        #pragma unroll
        for (int j = 0; j < 4; ++j)
          acc[i][j] += a[i]*b[j];
    }
    __syncthreads();
  }
  #pragma unroll
  for (int i = 0; i < 4; ++i){
    int gm = m0 + ty*4 + i;
    if (gm >= M) continue;
    int gn = n0 + tx*4;
    #pragma unroll
    for (int j = 0; j < 4; ++j)
      if (gn + j < Nn) C[(size_t)gm*Nn + gn + j] = acc[i][j];
  }
}

__global__ void k_attn8(const float* __restrict__ ht, const float* __restrict__ a_s,
                        const float* __restrict__ a_d, float* __restrict__ als,
                        float* __restrict__ ald, int N){
  int i = blockIdx.x*blockDim.x + threadIdx.x;
  if (i >= N*8) return;
  int h = i & 7;
  float v = ht[i];
  als[i] = v * a_s[h];
  ald[i] = v * a_d[h];
}

// ---------------------------------------------------------------------------
// aggregation: bf16 h (Pb, stride HC) + fp32 dots (D, stride 16).
// Fast path deg<64: lane-per-edge logits, tree reduce, alphas in LDS,
// feature pass reads alpha from LDS + src via shfl. Slow path: generic loops.
// ---------------------------------------------------------------------------
template<int HC, int ACT>
__global__ __launch_bounds__(256)
void k_agg(const unsigned short* __restrict__ Pb, const float* __restrict__ D,
           const int* __restrict__ off, const int* __restrict__ csr,
           const float* __restrict__ bias, float* __restrict__ outb, int N){
  constexpr int R = HC/64;
  __shared__ float salpha[4][512];
  int lane = threadIdx.x & 63;
  int wid  = threadIdx.x >> 6;
  int n = blockIdx.x*4 + wid;
  if (n >= N) return;
  int o0 = off[n], deg = off[n+1]-o0;
  int myh = lane >> 3;

  float aldn[8];
  {
    const float* dn = D + (size_t)n*16 + 8;
    float4 x0 = *(const float4*)dn;
    float4 x1 = *(const float4*)(dn+4);
    aldn[0]=x0.x; aldn[1]=x0.y; aldn[2]=x0.z; aldn[3]=x0.w;
    aldn[4]=x1.x; aldn[5]=x1.y; aldn[6]=x1.z; aldn[7]=x1.w;
  }

  float acc[R];
  #pragma unroll
  for (int j=0;j<R;++j) acc[j]=0.f;

  if (deg < 64){
    int nE = deg + 1;
    int myidx = (lane < deg) ? csr[o0+lane] : n;
    bool active = (lane < nE);
    float v[8];
    {
      const float* dp = D + (size_t)myidx*16;
      float4 x0 = *(const float4*)dp;
      float4 x1 = *(const float4*)(dp+4);
      float t[8] = {x0.x,x0.y,x0.z,x0.w,x1.x,x1.y,x1.z,x1.w};
      #pragma unroll
      for (int h=0;h<8;++h){
        float u = t[h] + aldn[h];
        u = u > 0.f ? u : 0.2f*u;
        v[h] = active ? u : -1e30f;
      }
    }
    float m[8];
    #pragma unroll
    for (int h=0;h<8;++h) m[h]=v[h];
    #pragma unroll
    for (int d=1; d<64; d<<=1)
      #pragma unroll
      for (int h=0;h<8;++h) m[h] = fmaxf(m[h], __shfl_xor(m[h], d, 64));
    float sv[8], s[8];
    #pragma unroll
    for (int h=0;h<8;++h){ sv[h] = active ? __expf(v[h]-m[h]) : 0.f; s[h]=sv[h]; }
    #pragma unroll
    for (int d=1; d<64; d<<=1)
      #pragma unroll
      for (int h=0;h<8;++h) s[h] += __shfl_xor(s[h], d, 64);
    if (active){
      #pragma unroll
      for (int h=0;h<8;++h) salpha[wid][lane*8+h] = sv[h] / (s[h] + 1e-16f);
    }
    asm volatile("s_waitcnt lgkmcnt(0)" ::: "memory");

    for (int e=0; e<nE; ++e){
      int src = __shfl(myidx, e, 64);
      float alpha = salpha[wid][e*8 + myh];
      const unsigned short* hp = Pb + (size_t)src*HC + lane*R;
      if constexpr (R == 1){
        acc[0] += alpha * bf2f(hp[0]);
      } else if constexpr (R == 4){
        short4v w = *(const short4v*)hp;
        #pragma unroll
        for (int j=0;j<4;++j) acc[j] += alpha * bf2f((unsigned short)w[j]);
      } else {
        short8 w = *(const short8*)hp;
        #pragma unroll
        for (int j=0;j<8;++j) acc[j] += alpha * bf2f((unsigned short)w[j]);
      }
    }
  } else {
    float m[8];
    #pragma unroll
    for (int h=0;h<8;++h) m[h] = -1e30f;
    for (int e = lane; e <= deg; e += 64){
      int src = (e < deg) ? csr[o0+e] : n;
      const float* ap = D + (size_t)src*16;
      #pragma unroll
      for (int h=0;h<8;++h){
        float u = ap[h] + aldn[h];
        u = u > 0.f ? u : 0.2f*u;
        m[h] = fmaxf(m[h], u);
      }
    }
    #pragma unroll
    for (int d=1; d<64; d<<=1)
      #pragma unroll
      for (int h=0;h<8;++h) m[h] = fmaxf(m[h], __shfl_xor(m[h], d, 64));
    float s[8] = {0,0,0,0,0,0,0,0};
    for (int e = lane; e <= deg; e += 64){
      int src = (e < deg) ? csr[o0+e] : n;
      const float* ap = D + (size_t)src*16;
      #pragma unroll
      for (int h=0;h<8;++h){
        float u = ap[h] + aldn[h];
        u = u > 0.f ? u : 0.2f*u;
        s[h] += __expf(u - m[h]);
      }
    }
    #pragma unroll
    for (int d=1; d<64; d<<=1)
      #pragma unroll
      for (int h=0;h<8;++h) s[h] += __shfl_xor(s[h], d, 64);
    float mh = m[myh];
    float rsh = 1.0f/(s[myh] + 1e-16f);
    float adh = aldn[myh];
    for (int e = 0; e <= deg; ++e){
      int src = (e < deg) ? csr[o0+e] : n;
      float u = D[(size_t)src*16 + myh] + adh;
      u = u > 0.f ? u : 0.2f*u;
      float alpha = __expf(u - mh) * rsh;
      const unsigned short* hp = Pb + (size_t)src*HC + lane*R;
      if constexpr (R == 1){
        acc[0] += alpha * bf2f(hp[0]);
      } else if constexpr (R == 4){
        short4v w = *(const short4v*)hp;
        #pragma unroll
        for (int j=0;j<4;++j) acc[j] += alpha * bf2f((unsigned short)w[j]);
      } else {
        short8 w = *(const short8*)hp;
        #pragma unroll
        for (int j=0;j<8;++j) acc[j] += alpha * bf2f((unsigned short)w[j]);
      }
    }
  }

  #pragma unroll
  for (int j = 0; j < R; ++j){
    int f = lane*R + j;
    float v = acc[j] + bias[f];
    if (ACT == 1) v = fmaxf(v, 0.0f);
    outb[(size_t)n*HC + f] = v;
  }
}

// ---------------------------------------------------------------------------
// BatchNorm stats + apply(+leaky_relu 0.1)
// ---------------------------------------------------------------------------
__global__ void k_bn_stats(const float* __restrict__ x, float* __restrict__ gsum,
                           float* __restrict__ gsq, int N, int HC){
  int f = threadIdx.x;
  float s = 0.f, q = 0.f;
  for (int r = blockIdx.x; r < N; r += gridDim.x){
    float v = x[(size_t)r*HC + f];
    s += v; q += v*v;
  }
  atomicAdd(&gsum[f], s);
  atomicAdd(&gsq[f], q);
}

__global__ void k_bn_apply(float* __restrict__ x, const float* __restrict__ gsum,
                           const float* __restrict__ gsq, const float* __restrict__ g,
                           const float* __restrict__ b, int N, int HC){
  int i = blockIdx.x*blockDim.x + threadIdx.x;
  int total = N*HC;
  if (i >= total) return;
  int f = i % HC;
  float inv = 1.0f/(float)N;
  float mu  = gsum[f]*inv;
  float var = gsq[f]*inv - mu*mu;
  float v = (x[i]-mu)*rsqrtf(var+1e-5f)*g[f] + b[f];
  x[i] = v > 0.f ? v : 0.1f*v;
}

// ---------------------------------------------------------------------------
// final conv (512->1, 8 heads, mean, sigmoid)
// ---------------------------------------------------------------------------
__global__ void k_final(const float* __restrict__ ht8, const float* __restrict__ als,
                        const float* __restrict__ ald, const int* __restrict__ off,
                        const int* __restrict__ csr, const float* __restrict__ b32,
                        float* __restrict__ outp, int N){
  int n = blockIdx.x*blockDim.x + threadIdx.x;
  if (n >= N) return;
  int o0 = off[n], deg = off[n+1]-o0;
  float aldn[8], m[8], s[8], agg[8];
  #pragma unroll
  for (int h = 0; h < 8; ++h){ aldn[h] = ald[n*8+h]; m[h] = -1e30f; s[h]=0.f; agg[h]=0.f; }
  for (int e = 0; e <= deg; ++e){
    int src = (e < deg) ? csr[o0+e] : n;
    #pragma unroll
    for (int h = 0; h < 8; ++h){
      float v = als[(size_t)src*8+h] + aldn[h];
      v = v > 0.f ? v : 0.2f*v;
      m[h] = fmaxf(m[h], v);
    }
  }
  for (int e = 0; e <= deg; ++e){
    int src = (e < deg) ? csr[o0+e] : n;
    #pragma unroll
    for (int h = 0; h < 8; ++h){
      float v = als[(size_t)src*8+h] + aldn[h];
      v = v > 0.f ? v : 0.2f*v;
      float ex = __expf(v - m[h]);
      s[h] += ex;
      agg[h] += ex * ht8[(size_t)src*8+h];
    }
  }
  float o = 0.f;
  #pragma unroll
  for (int h = 0; h < 8; ++h) o += agg[h]/(s[h]+1e-16f);
  o = o*0.125f + b32[0];
  outp[n] = 1.0f/(1.0f + __expf(-o));
}

// ---------------------------------------------------------------------------
extern "C" void kernel_launch(void* const* d_in, const int* in_sizes, int n_in,
                              void* d_out, int out_size, void* d_ws, size_t ws_size,
                              hipStream_t stream){
  int N = in_sizes[0]/3;
  int E = in_sizes[1]/2;
  const float* x    = (const float*)d_in[0];
  const int*   ei   = (const int*)  d_in[1];
  const float* W11  = (const float*)d_in[2];
  const float* as11 = (const float*)d_in[3];
  const float* ad11 = (const float*)d_in[4];
  const float* b11  = (const float*)d_in[5];
  const float* W12  = (const float*)d_in[6];
  const float* as12 = (const float*)d_in[7];
  const float* ad12 = (const float*)d_in[8];
  const float* b12  = (const float*)d_in[9];
  const float* g1   = (const float*)d_in[10];
  const float* be1  = (const float*)d_in[11];
  const float* W21  = (const float*)d_in[12];
  const float* as21 = (const float*)d_in[13];
  const float* ad21 = (const float*)d_in[14];
  const float* b21  = (const float*)d_in[15];
  const float* W22  = (const float*)d_in[16];
  const float* as22 = (const float*)d_in[17];
  const float* ad22 = (const float*)d_in[18];
  const float* b22  = (const float*)d_in[19];
  const float* g2   = (const float*)d_in[20];
  const float* be2  = (const float*)d_in[21];
  const float* W31  = (const float*)d_in[22];
  const float* as31 = (const float*)d_in[23];
  const float* ad31 = (const float*)d_in[24];
  const float* b31  = (const float*)d_in[25];
  const float* W32  = (const float*)d_in[26];
  const float* as32 = (const float*)d_in[27];
  const float* ad32 = (const float*)d_in[28];
  const float* b32  = (const float*)d_in[29];

  char* ws = (char*)d_ws;
  size_t o = 0;
  auto alloc = [&](size_t bytes)->char*{
    char* p = ws + o;
    o = (o + bytes + 255) & ~(size_t)255;
    return p;
  };
  int*   deg    = (int*)  alloc((size_t)N*4);
  int*   off    = (int*)  alloc((size_t)(N+1)*4);
  int*   cursor = (int*)  alloc((size_t)N*4);
  int*   csr    = (int*)  alloc((size_t)E*4);
  unsigned short* bth = (unsigned short*)alloc(131072*2);
  unsigned short* btl = (unsigned short*)alloc(131072*2);
  float* als8   = (float*)alloc((size_t)N*8*4);
  float* ald8   = (float*)alloc((size_t)N*8*4);
  float* h8     = (float*)alloc((size_t)N*8*4);
  float* bsum   = (float*)alloc(256*4);
  float* bsq    = (float*)alloc(256*4);
  unsigned short* Pb = (unsigned short*)alloc((size_t)N*512*2); // bf16 h
  float* D      = (float*)alloc((size_t)N*16*4);                // fp32 dots
  float* Q      = (float*)alloc((size_t)N*512*4);               // post-agg fp32
  (void)ws_size;

  // ---- CSR build ----
  hipMemsetAsync(deg, 0, (size_t)N*4, stream);
  int eb = (E+255)/256;
  k_deg <<<eb, 256, 0, stream>>>(ei+E, deg, E);
  k_scan<<<1, 1024, 0, stream>>>(deg, off, cursor, N);
  k_fill<<<eb, 256, 0, stream>>>(ei, ei+E, cursor, csr, E);

  int mb = (N+63)/64;
  int nb4 = (N+3)/4;

  // ---- conv11: 3 -> 64, relu ----
  k_prepB<<<(64*64)/256, 256, 0, stream>>>(W11, bth, btl, 3, 6, 64);
  gemm_mfma<64><<<mb, 256, 0, stream>>>(x, bth, btl, as11, ad11, Pb, D, N, 3);
  k_agg<64,1><<<nb4, 256, 0, stream>>>(Pb, D, off, csr, b11, Q, N);

  // ---- conv12: 64 -> 64, BN + lrelu(0.1) ----
  k_prepB<<<(64*64)/256, 256, 0, stream>>>(W12, bth, btl, 64, 6, 64);
  gemm_mfma<64><<<mb, 256, 0, stream>>>(Q, bth, btl, as12, ad12, Pb, D, N, 64);
  k_agg<64,0><<<nb4, 256, 0, stream>>>(Pb, D, off, csr, b12, Q, N);
  hipMemsetAsync(bsum, 0, 64*4, stream);
  hipMemsetAsync(bsq,  0, 64*4, stream);
  k_bn_stats<<<512, 64, 0, stream>>>(Q, bsum, bsq, N, 64);
  k_bn_apply<<<(N*64+255)/256, 256, 0, stream>>>(Q, bsum, bsq, g1, be1, N, 64);

  // ---- conv21: 64 -> 256, relu ----
  k_prepB<<<(256*64)/256, 256, 0, stream>>>(W21, bth, btl, 64, 6, 256);
  gemm_mfma<256><<<mb, 512, 0, stream>>>(Q, bth, btl, as21, ad21, Pb, D, N, 64);
  k_agg<256,1><<<nb4, 256, 0, stream>>>(Pb, D, off, csr, b21, Q, N);

  // ---- conv22: 256 -> 256, BN + lrelu(0.1) ----
  k_prepB<<<(256*256)/256, 256, 0, stream>>>(W22, bth, btl, 256, 8, 256);
  gemm_mfma<256><<<mb, 512, 0, stream>>>(Q, bth, btl, as22, ad22, Pb, D, N, 256);
  k_agg<256,0><<<nb4, 256, 0, stream>>>(Pb, D, off, csr, b22, Q, N);
  hipMemsetAsync(bsum, 0, 256*4, stream);
  hipMemsetAsync(bsq,  0, 256*4, stream);
  k_bn_stats<<<512, 256, 0, stream>>>(Q, bsum, bsq, N, 256);
  k_bn_apply<<<(N*256+255)/256, 256, 0, stream>>>(Q, bsum, bsq, g2, be2, N, 256);

  // ---- conv31: 256 -> 512, relu ----
  k_prepB<<<(512*256)/256, 256, 0, stream>>>(W31, bth, btl, 256, 8, 512);
  gemm_mfma<512><<<mb, 512, 0, stream>>>(Q, bth, btl, as31, ad31, Pb, D, N, 256);
  k_agg<512,1><<<nb4, 256, 0, stream>>>(Pb, D, off, csr, b31, Q, N);

  // ---- conv32: 512 -> 8x1, concat=False, mean, sigmoid ----
  {
    dim3 g((N+63)/64, 1);
    gemm_f32<<<g, 256, 0, stream>>>(Q, W32, h8, N, 512, 8);
  }
  k_attn8<<<(N*8+255)/256, 256, 0, stream>>>(h8, as32, ad32, als8, ald8, N);
  k_final<<<(N+255)/256, 256, 0, stream>>>(h8, als8, ald8, off, csr, b32,
                                           (float*)d_out, N);
}

// Round 4
// 1145.821 us; speedup vs baseline: 1.5699x; 1.0918x over previous
//
#include <hip/hip_runtime.h>
#include <math.h>

typedef short short8 __attribute__((ext_vector_type(8)));
typedef short short4v __attribute__((ext_vector_type(4)));
typedef float f32x4 __attribute__((ext_vector_type(4)));

__device__ __forceinline__ unsigned short f2bf(float v){
  unsigned u = __builtin_bit_cast(unsigned, v);
  u += 0x7FFFu + ((u >> 16) & 1u);
  return (unsigned short)(u >> 16);
}
__device__ __forceinline__ float bf2f(unsigned short b){
  unsigned u = ((unsigned)b) << 16;
  return __builtin_bit_cast(float, u);
}

// ---------------------------------------------------------------------------
// CSR build (by dst)
// ---------------------------------------------------------------------------
__global__ void k_deg(const int* __restrict__ dstv, int* __restrict__ deg, int E){
  int e = blockIdx.x*blockDim.x + threadIdx.x;
  if (e < E) atomicAdd(&deg[dstv[e]], 1);
}

// single-block scan, shfl-based (1024 thr = 16 waves)
__global__ void k_scan(const int* __restrict__ deg, int* __restrict__ off,
                       int* __restrict__ cursor, int N){
  __shared__ int wpre[16];
  __shared__ int s_tot;
  __shared__ int carry;
  int tid = threadIdx.x;
  int lane = tid & 63, wv = tid >> 6;
  if (tid == 0) carry = 0;
  __syncthreads();
  for (int base = 0; base < N; base += 1024){
    int i = base + tid;
    int v = (i < N) ? deg[i] : 0;
    int incl = v;
    #pragma unroll
    for (int d = 1; d < 64; d <<= 1){
      int t = __shfl_up(incl, d, 64);
      if (lane >= d) incl += t;
    }
    if (lane == 63) wpre[wv] = incl;
    __syncthreads();
    if (tid < 16){
      int x = wpre[tid];
      int ix = x;
      #pragma unroll
      for (int d = 1; d < 16; d <<= 1){
        int t = __shfl_up(ix, d, 16);
        if (tid >= d) ix += t;
      }
      wpre[tid] = ix - x;            // exclusive prefix of wave sums
      if (tid == 15) s_tot = ix;     // tile total
    }
    __syncthreads();
    int c = carry;
    int excl = c + wpre[wv] + (incl - v);
    if (i < N){ off[i+1] = excl + v; cursor[i] = excl; }
    __syncthreads();
    if (tid == 0) carry = c + s_tot;
    __syncthreads();
  }
  if (tid == 0) off[0] = 0;
}

__global__ void k_fill(const int* __restrict__ srcv, const int* __restrict__ dstv,
                       int* __restrict__ cursor, int* __restrict__ csr, int E){
  int e = blockIdx.x*blockDim.x + threadIdx.x;
  if (e < E){
    int d = dstv[e];
    int p = atomicAdd(&cursor[d], 1);
    csr[p] = srcv[e];
  }
}

// ---------------------------------------------------------------------------
// B pre-convert: W fp32 [K, Nn] -> Bt_hi/Bt_lo bf16 [Nn][Kp]
// ---------------------------------------------------------------------------
__global__ void k_prepB(const float* __restrict__ W, unsigned short* __restrict__ bh,
                        unsigned short* __restrict__ bl, int K, int kpshift, int Nn){
  int Kp = 1 << kpshift;
  int i = blockIdx.x*blockDim.x + threadIdx.x;
  if (i >= Nn*Kp) return;
  int n = i >> kpshift, k = i & (Kp-1);
  float v = (k < K) ? W[(size_t)k*Nn + n] : 0.0f;
  unsigned short h = f2bf(v);
  bh[i] = h;
  bl[i] = f2bf(v - bf2f(h));
}

// ---------------------------------------------------------------------------
// BN coef: scale/shift from accumulated stats
// ---------------------------------------------------------------------------
__global__ void k_bn_coef(const float* __restrict__ bsum, const float* __restrict__ bsq,
                          const float* __restrict__ g, const float* __restrict__ b,
                          float* __restrict__ sc, float* __restrict__ sh,
                          float invN, int HC){
  int f = threadIdx.x + blockIdx.x*blockDim.x;
  if (f >= HC) return;
  float mu  = bsum[f]*invN;
  float var = bsq[f]*invN - mu*mu;
  float rs  = rsqrtf(var + 1e-5f) * g[f];
  sc[f] = rs;
  sh[f] = b[f] - mu*rs;
}

// ---------------------------------------------------------------------------
// bf16x3 MFMA GEMM. BM=64, BN = full width. MODE=1 fuses BN affine + lrelu(0.1)
// into the A-staging. Epilogue: h -> bf16 Pb (stride BN), dots -> fp32 D.
// ---------------------------------------------------------------------------
template<int BN, int MODE>
__global__ __launch_bounds__((BN==64)?256:512)
void gemm_mfma(const float* __restrict__ A, const unsigned short* __restrict__ Bh,
               const unsigned short* __restrict__ Bl,
               const float* __restrict__ bnsc, const float* __restrict__ bnsh,
               const float* __restrict__ a_s, const float* __restrict__ a_d,
               unsigned short* __restrict__ Pb, float* __restrict__ D, int M, int K){
  constexpr int WAVES   = (BN==64) ? 4 : 8;
  constexpr int BLOCK   = WAVES*64;
  constexpr int WAVES_N = BN/64;
  constexpr int WAVES_M = WAVES/WAVES_N;
  constexpr int WM      = 64/WAVES_M;
  constexpr int MF      = WM/16;
  constexpr int CH      = (BN==512)?64 : (BN==256)?32 : 8;
  const int Kp = (K + 63) & ~(int)63;

  __shared__ char lds[16384];

  int tid  = threadIdx.x;
  int lane = tid & 63;
  int wid  = tid >> 6;
  int wn = wid % WAVES_N;
  int wm = wid / WAVES_N;
  int n0w = wn*64;
  int wm0 = wm*WM;
  int m0 = blockIdx.x * 64;

  f32x4 acc[MF][4];
  #pragma unroll
  for (int i = 0; i < MF; ++i)
    #pragma unroll
    for (int j = 0; j < 4; ++j)
      acc[i][j] = (f32x4){0.f,0.f,0.f,0.f};

  constexpr int SITER = 512/BLOCK;

  for (int k0 = 0; k0 < Kp; k0 += 64){
    __syncthreads();
    #pragma unroll
    for (int it = 0; it < SITER; ++it){
      int i = it*BLOCK + tid;
      int row = i >> 3, c8 = i & 7;
      int gm = m0 + row;
      int gk = k0 + c8*8;
      float v[8];
      if (gm < M && gk + 8 <= K){
        const float* ap = A + (size_t)gm*K + gk;
        float4 x0 = *(const float4*)ap;
        float4 x1 = *(const float4*)(ap+4);
        v[0]=x0.x; v[1]=x0.y; v[2]=x0.z; v[3]=x0.w;
        v[4]=x1.x; v[5]=x1.y; v[6]=x1.z; v[7]=x1.w;
        if constexpr (MODE == 1){
          #pragma unroll
          for (int j=0;j<8;++j){
            float u = v[j]*bnsc[gk+j] + bnsh[gk+j];
            v[j] = u > 0.f ? u : 0.1f*u;
          }
        }
      } else {
        #pragma unroll
        for (int j=0;j<8;++j){
          int gkj = gk + j;
          bool ok = (gm < M && gkj < K);
          float u = ok ? A[(size_t)gm*K + gkj] : 0.0f;
          if constexpr (MODE == 1){
            if (ok){
              u = u*bnsc[gkj] + bnsh[gkj];
              u = u > 0.f ? u : 0.1f*u;
            }
          }
          v[j] = u;
        }
      }
      short8 hi, lo;
      #pragma unroll
      for (int j=0;j<8;++j){
        unsigned short hb = f2bf(v[j]);
        hi[j] = (short)hb;
        lo[j] = (short)f2bf(v[j] - bf2f(hb));
      }
      int off = row*128 + ((c8 ^ (row&7))<<4);
      *(short8*)(lds + off) = hi;
      *(short8*)(lds + 8192 + off) = lo;
    }
    __syncthreads();
    #pragma unroll
    for (int kk = 0; kk < 2; ++kk){
      short8 bhf[4], blf[4];
      #pragma unroll
      for (int nf = 0; nf < 4; ++nf){
        int ncol = n0w + nf*16 + (lane & 15);
        int kidx = k0 + kk*32 + ((lane>>4)<<3);
        size_t bo = (size_t)ncol*Kp + kidx;
        bhf[nf] = *(const short8*)(Bh + bo);
        blf[nf] = *(const short8*)(Bl + bo);
      }
      #pragma unroll
      for (int mt = 0; mt < MF; ++mt){
        int row = wm0 + mt*16 + (lane & 15);
        int c8 = kk*4 + (lane>>4);
        int off = row*128 + ((c8 ^ (row&7))<<4);
        short8 ah = *(const short8*)(lds + off);
        short8 al = *(const short8*)(lds + 8192 + off);
        #pragma unroll
        for (int nf = 0; nf < 4; ++nf){
          acc[mt][nf] = __builtin_amdgcn_mfma_f32_16x16x32_bf16(ah, bhf[nf], acc[mt][nf], 0,0,0);
          acc[mt][nf] = __builtin_amdgcn_mfma_f32_16x16x32_bf16(ah, blf[nf], acc[mt][nf], 0,0,0);
          acc[mt][nf] = __builtin_amdgcn_mfma_f32_16x16x32_bf16(al, bhf[nf], acc[mt][nf], 0,0,0);
        }
      }
    }
  }

  float asv[4], adv[4];
  #pragma unroll
  for (int nf=0; nf<4; ++nf){
    int gcol = n0w + nf*16 + (lane&15);
    asv[nf] = a_s[gcol];
    adv[nf] = a_d[gcol];
  }
  #pragma unroll
  for (int mt = 0; mt < MF; ++mt){
    #pragma unroll
    for (int r = 0; r < 4; ++r){
      int gm = m0 + wm0 + mt*16 + ((lane>>4)<<2) + r;
      bool ok = gm < M;
      #pragma unroll
      for (int nf=0;nf<4;++nf){
        if (ok) Pb[(size_t)gm*BN + n0w + nf*16 + (lane&15)] = f2bf(acc[mt][nf][r]);
      }
      float* dp = D + (size_t)gm*16;
      if constexpr (CH == 64){
        float ps = acc[mt][0][r]*asv[0] + acc[mt][1][r]*asv[1]
                 + acc[mt][2][r]*asv[2] + acc[mt][3][r]*asv[3];
        float pd = acc[mt][0][r]*adv[0] + acc[mt][1][r]*adv[1]
                 + acc[mt][2][r]*adv[2] + acc[mt][3][r]*adv[3];
        #pragma unroll
        for (int d2=1; d2<16; d2<<=1){ ps += __shfl_xor(ps,d2,64); pd += __shfl_xor(pd,d2,64); }
        if (ok && (lane&15)==0){
          int head = n0w >> 6;
          dp[head] = ps;
          dp[8 + head] = pd;
        }
      } else if constexpr (CH == 32){
        float ps0 = acc[mt][0][r]*asv[0] + acc[mt][1][r]*asv[1];
        float ps1 = acc[mt][2][r]*asv[2] + acc[mt][3][r]*asv[3];
        float pd0 = acc[mt][0][r]*adv[0] + acc[mt][1][r]*adv[1];
        float pd1 = acc[mt][2][r]*adv[2] + acc[mt][3][r]*adv[3];
        #pragma unroll
        for (int d2=1; d2<16; d2<<=1){
          ps0 += __shfl_xor(ps0,d2,64); ps1 += __shfl_xor(ps1,d2,64);
          pd0 += __shfl_xor(pd0,d2,64); pd1 += __shfl_xor(pd1,d2,64);
        }
        if (ok && (lane&15)==0){
          int head = n0w >> 5;
          dp[head]     = ps0;
          dp[head + 1] = ps1;
          dp[8 + head]     = pd0;
          dp[8 + head + 1] = pd1;
        }
      } else {
        #pragma unroll
        for (int nf=0;nf<4;++nf){
          float ps = acc[mt][nf][r]*asv[nf];
          float pd = acc[mt][nf][r]*adv[nf];
          #pragma unroll
          for (int d2=1; d2<8; d2<<=1){ ps += __shfl_xor(ps,d2,64); pd += __shfl_xor(pd,d2,64); }
          if (ok && (lane&7)==0){
            int head = nf*2 + ((lane>>3)&1);
            dp[head]     = ps;
            dp[8 + head] = pd;
          }
        }
      }
    }
  }
}

// ---------------------------------------------------------------------------
// aggregation: bf16 h (Pb, stride HC) + fp32 dots (D, stride 16).
// OBF=1 writes bf16 output. Fast path deg<64; generic slow path.
// ---------------------------------------------------------------------------
template<int HC, int ACT, int OBF>
__global__ __launch_bounds__(256)
void k_agg(const unsigned short* __restrict__ Pb, const float* __restrict__ D,
           const int* __restrict__ off, const int* __restrict__ csr,
           const float* __restrict__ bias, void* __restrict__ outv, int N){
  constexpr int R = HC/64;
  __shared__ float salpha[4][512];
  int lane = threadIdx.x & 63;
  int wid  = threadIdx.x >> 6;
  int n = blockIdx.x*4 + wid;
  if (n >= N) return;
  int o0 = off[n], deg = off[n+1]-o0;
  int myh = lane >> 3;

  float aldn[8];
  {
    const float* dn = D + (size_t)n*16 + 8;
    float4 x0 = *(const float4*)dn;
    float4 x1 = *(const float4*)(dn+4);
    aldn[0]=x0.x; aldn[1]=x0.y; aldn[2]=x0.z; aldn[3]=x0.w;
    aldn[4]=x1.x; aldn[5]=x1.y; aldn[6]=x1.z; aldn[7]=x1.w;
  }

  float acc[R];
  #pragma unroll
  for (int j=0;j<R;++j) acc[j]=0.f;

  if (deg < 64){
    int nE = deg + 1;
    int myidx = (lane < deg) ? csr[o0+lane] : n;
    bool active = (lane < nE);
    float v[8];
    {
      const float* dp = D + (size_t)myidx*16;
      float4 x0 = *(const float4*)dp;
      float4 x1 = *(const float4*)(dp+4);
      float t[8] = {x0.x,x0.y,x0.z,x0.w,x1.x,x1.y,x1.z,x1.w};
      #pragma unroll
      for (int h=0;h<8;++h){
        float u = t[h] + aldn[h];
        u = u > 0.f ? u : 0.2f*u;
        v[h] = active ? u : -1e30f;
      }
    }
    float m[8];
    #pragma unroll
    for (int h=0;h<8;++h) m[h]=v[h];
    #pragma unroll
    for (int d=1; d<64; d<<=1)
      #pragma unroll
      for (int h=0;h<8;++h) m[h] = fmaxf(m[h], __shfl_xor(m[h], d, 64));
    float sv[8], s[8];
    #pragma unroll
    for (int h=0;h<8;++h){ sv[h] = active ? __expf(v[h]-m[h]) : 0.f; s[h]=sv[h]; }
    #pragma unroll
    for (int d=1; d<64; d<<=1)
      #pragma unroll
      for (int h=0;h<8;++h) s[h] += __shfl_xor(s[h], d, 64);
    if (active){
      #pragma unroll
      for (int h=0;h<8;++h) salpha[wid][lane*8+h] = sv[h] / (s[h] + 1e-16f);
    }
    asm volatile("s_waitcnt lgkmcnt(0)" ::: "memory");

    for (int e=0; e<nE; ++e){
      int src = __shfl(myidx, e, 64);
      float alpha = salpha[wid][e*8 + myh];
      const unsigned short* hp = Pb + (size_t)src*HC + lane*R;
      if constexpr (R == 1){
        acc[0] += alpha * bf2f(hp[0]);
      } else if constexpr (R == 4){
        short4v w = *(const short4v*)hp;
        #pragma unroll
        for (int j=0;j<4;++j) acc[j] += alpha * bf2f((unsigned short)w[j]);
      } else {
        short8 w = *(const short8*)hp;
        #pragma unroll
        for (int j=0;j<8;++j) acc[j] += alpha * bf2f((unsigned short)w[j]);
      }
    }
  } else {
    float m[8];
    #pragma unroll
    for (int h=0;h<8;++h) m[h] = -1e30f;
    for (int e = lane; e <= deg; e += 64){
      int src = (e < deg) ? csr[o0+e] : n;
      const float* ap = D + (size_t)src*16;
      #pragma unroll
      for (int h=0;h<8;++h){
        float u = ap[h] + aldn[h];
        u = u > 0.f ? u : 0.2f*u;
        m[h] = fmaxf(m[h], u);
      }
    }
    #pragma unroll
    for (int d=1; d<64; d<<=1)
      #pragma unroll
      for (int h=0;h<8;++h) m[h] = fmaxf(m[h], __shfl_xor(m[h], d, 64));
    float s[8] = {0,0,0,0,0,0,0,0};
    for (int e = lane; e <= deg; e += 64){
      int src = (e < deg) ? csr[o0+e] : n;
      const float* ap = D + (size_t)src*16;
      #pragma unroll
      for (int h=0;h<8;++h){
        float u = ap[h] + aldn[h];
        u = u > 0.f ? u : 0.2f*u;
        s[h] += __expf(u - m[h]);
      }
    }
    #pragma unroll
    for (int d=1; d<64; d<<=1)
      #pragma unroll
      for (int h=0;h<8;++h) s[h] += __shfl_xor(s[h], d, 64);
    float mh = m[myh];
    float rsh = 1.0f/(s[myh] + 1e-16f);
    float adh = aldn[myh];
    for (int e = 0; e <= deg; ++e){
      int src = (e < deg) ? csr[o0+e] : n;
      float u = D[(size_t)src*16 + myh] + adh;
      u = u > 0.f ? u : 0.2f*u;
      float alpha = __expf(u - mh) * rsh;
      const unsigned short* hp = Pb + (size_t)src*HC + lane*R;
      if constexpr (R == 1){
        acc[0] += alpha * bf2f(hp[0]);
      } else if constexpr (R == 4){
        short4v w = *(const short4v*)hp;
        #pragma unroll
        for (int j=0;j<4;++j) acc[j] += alpha * bf2f((unsigned short)w[j]);
      } else {
        short8 w = *(const short8*)hp;
        #pragma unroll
        for (int j=0;j<8;++j) acc[j] += alpha * bf2f((unsigned short)w[j]);
      }
    }
  }

  #pragma unroll
  for (int j = 0; j < R; ++j){
    int f = lane*R + j;
    float v = acc[j] + bias[f];
    if (ACT == 1) v = fmaxf(v, 0.0f);
    if constexpr (OBF == 1)
      ((unsigned short*)outv)[(size_t)n*HC + f] = f2bf(v);
    else
      ((float*)outv)[(size_t)n*HC + f] = v;
  }
}

// ---------------------------------------------------------------------------
// BatchNorm stats
// ---------------------------------------------------------------------------
__global__ void k_bn_stats(const float* __restrict__ x, float* __restrict__ gsum,
                           float* __restrict__ gsq, int N, int HC){
  int f = threadIdx.x;
  float s = 0.f, q = 0.f;
  for (int r = blockIdx.x; r < N; r += gridDim.x){
    float v = x[(size_t)r*HC + f];
    s += v; q += v*v;
  }
  atomicAdd(&gsum[f], s);
  atomicAdd(&gsq[f], q);
}

// ---------------------------------------------------------------------------
// conv32 GEMM: bf16 A [M,512] x fp32 W [512,8] -> fp32 h8 [M,8].
// Wave-per-row, W held in registers (each lane: rows lane*8..lane*8+7).
// ---------------------------------------------------------------------------
__global__ __launch_bounds__(256)
void gemm8(const unsigned short* __restrict__ Qb, const float* __restrict__ W,
           float* __restrict__ h8, int M){
  int lane = threadIdx.x & 63;
  int gw = (blockIdx.x*blockDim.x + threadIdx.x) >> 6;
  int nw = (gridDim.x*blockDim.x) >> 6;
  float w[8][8];
  const float* wp = W + lane*64;
  #pragma unroll
  for (int j=0;j<8;++j){
    float4 a = *(const float4*)(wp + j*8);
    float4 b = *(const float4*)(wp + j*8 + 4);
    w[j][0]=a.x; w[j][1]=a.y; w[j][2]=a.z; w[j][3]=a.w;
    w[j][4]=b.x; w[j][5]=b.y; w[j][6]=b.z; w[j][7]=b.w;
  }
  for (int n = gw; n < M; n += nw){
    short8 v8 = *(const short8*)(Qb + (size_t)n*512 + lane*8);
    float p[8] = {0,0,0,0,0,0,0,0};
    #pragma unroll
    for (int j=0;j<8;++j){
      float x = bf2f((unsigned short)v8[j]);
      #pragma unroll
      for (int o=0;o<8;++o) p[o] += x * w[j][o];
    }
    #pragma unroll
    for (int d=1; d<64; d<<=1)
      #pragma unroll
      for (int o=0;o<8;++o) p[o] += __shfl_xor(p[o], d, 64);
    if (lane == 0){
      float4 y0 = make_float4(p[0],p[1],p[2],p[3]);
      float4 y1 = make_float4(p[4],p[5],p[6],p[7]);
      *(float4*)(h8 + (size_t)n*8)     = y0;
      *(float4*)(h8 + (size_t)n*8 + 4) = y1;
    }
  }
}

// ---------------------------------------------------------------------------
// final conv: wave-per-node, single gather of h8[src] per edge; fused attn
// dots, softmax, mean over heads, +b, sigmoid.
// ---------------------------------------------------------------------------
__global__ __launch_bounds__(256)
void k_final(const float* __restrict__ h8, const float* __restrict__ a_s,
             const float* __restrict__ a_d, const int* __restrict__ off,
             const int* __restrict__ csr, const float* __restrict__ b32,
             float* __restrict__ outp, int N){
  int lane = threadIdx.x & 63;
  int wv   = threadIdx.x >> 6;
  int n = blockIdx.x*4 + wv;
  if (n >= N) return;
  int o0 = off[n], deg = off[n+1]-o0;
  float asv[8], adv[8];
  #pragma unroll
  for (int h=0;h<8;++h){ asv[h]=a_s[h]; adv[h]=a_d[h]; }
  float aldn[8];
  {
    const float* hp = h8 + (size_t)n*8;
    float4 x0 = *(const float4*)hp;
    float4 x1 = *(const float4*)(hp+4);
    float hn[8] = {x0.x,x0.y,x0.z,x0.w,x1.x,x1.y,x1.z,x1.w};
    #pragma unroll
    for (int h=0;h<8;++h) aldn[h] = hn[h]*adv[h];
  }

  if (deg < 64){
    int nE = deg + 1;
    int src = (lane < deg) ? csr[o0+lane] : n;
    bool act = (lane < nE);
    float hs[8];
    {
      const float* hp = h8 + (size_t)src*8;
      float4 x0 = *(const float4*)hp;
      float4 x1 = *(const float4*)(hp+4);
      hs[0]=x0.x; hs[1]=x0.y; hs[2]=x0.z; hs[3]=x0.w;
      hs[4]=x1.x; hs[5]=x1.y; hs[6]=x1.z; hs[7]=x1.w;
    }
    float v[8];
    #pragma unroll
    for (int h=0;h<8;++h){
      float u = hs[h]*asv[h] + aldn[h];
      u = u > 0.f ? u : 0.2f*u;
      v[h] = act ? u : -1e30f;
    }
    float m[8];
    #pragma unroll
    for (int h=0;h<8;++h) m[h]=v[h];
    #pragma unroll
    for (int d=1; d<64; d<<=1)
      #pragma unroll
      for (int h=0;h<8;++h) m[h] = fmaxf(m[h], __shfl_xor(m[h], d, 64));
    float s[8], t[8];
    #pragma unroll
    for (int h=0;h<8;++h){
      float e = act ? __expf(v[h]-m[h]) : 0.f;
      s[h]=e; t[h]=e*hs[h];
    }
    #pragma unroll
    for (int d=1; d<64; d<<=1)
      #pragma unroll
      for (int h=0;h<8;++h){
        s[h] += __shfl_xor(s[h], d, 64);
        t[h] += __shfl_xor(t[h], d, 64);
      }
    if (lane == 0){
      float o = 0.f;
      #pragma unroll
      for (int h=0;h<8;++h) o += t[h]/(s[h]+1e-16f);
      o = o*0.125f + b32[0];
      outp[n] = 1.0f/(1.0f + __expf(-o));
    }
  } else if (lane == 0){
    float m[8], s[8], agg[8];
    #pragma unroll
    for (int h=0;h<8;++h){ m[h]=-1e30f; s[h]=0.f; agg[h]=0.f; }
    for (int e = 0; e <= deg; ++e){
      int src = (e < deg) ? csr[o0+e] : n;
      #pragma unroll
      for (int h=0;h<8;++h){
        float u = h8[(size_t)src*8+h]*asv[h] + aldn[h];
        u = u > 0.f ? u : 0.2f*u;
        m[h] = fmaxf(m[h], u);
      }
    }
    for (int e = 0; e <= deg; ++e){
      int src = (e < deg) ? csr[o0+e] : n;
      #pragma unroll
      for (int h=0;h<8;++h){
        float u = h8[(size_t)src*8+h]*asv[h] + aldn[h];
        u = u > 0.f ? u : 0.2f*u;
        float ex = __expf(u - m[h]);
        s[h] += ex;
        agg[h] += ex * h8[(size_t)src*8+h];
      }
    }
    float o = 0.f;
    #pragma unroll
    for (int h=0;h<8;++h) o += agg[h]/(s[h]+1e-16f);
    o = o*0.125f + b32[0];
    outp[n] = 1.0f/(1.0f + __expf(-o));
  }
}

// ---------------------------------------------------------------------------
extern "C" void kernel_launch(void* const* d_in, const int* in_sizes, int n_in,
                              void* d_out, int out_size, void* d_ws, size_t ws_size,
                              hipStream_t stream){
  int N = in_sizes[0]/3;
  int E = in_sizes[1]/2;
  const float* x    = (const float*)d_in[0];
  const int*   ei   = (const int*)  d_in[1];
  const float* W11  = (const float*)d_in[2];
  const float* as11 = (const float*)d_in[3];
  const float* ad11 = (const float*)d_in[4];
  const float* b11  = (const float*)d_in[5];
  const float* W12  = (const float*)d_in[6];
  const float* as12 = (const float*)d_in[7];
  const float* ad12 = (const float*)d_in[8];
  const float* b12  = (const float*)d_in[9];
  const float* g1   = (const float*)d_in[10];
  const float* be1  = (const float*)d_in[11];
  const float* W21  = (const float*)d_in[12];
  const float* as21 = (const float*)d_in[13];
  const float* ad21 = (const float*)d_in[14];
  const float* b21  = (const float*)d_in[15];
  const float* W22  = (const float*)d_in[16];
  const float* as22 = (const float*)d_in[17];
  const float* ad22 = (const float*)d_in[18];
  const float* b22  = (const float*)d_in[19];
  const float* g2   = (const float*)d_in[20];
  const float* be2  = (const float*)d_in[21];
  const float* W31  = (const float*)d_in[22];
  const float* as31 = (const float*)d_in[23];
  const float* ad31 = (const float*)d_in[24];
  const float* b31  = (const float*)d_in[25];
  const float* W32  = (const float*)d_in[26];
  const float* as32 = (const float*)d_in[27];
  const float* ad32 = (const float*)d_in[28];
  const float* b32  = (const float*)d_in[29];

  char* ws = (char*)d_ws;
  size_t o = 0;
  auto alloc = [&](size_t bytes)->char*{
    char* p = ws + o;
    o = (o + bytes + 255) & ~(size_t)255;
    return p;
  };
  int*   deg    = (int*)  alloc((size_t)N*4);
  int*   off    = (int*)  alloc((size_t)(N+1)*4);
  int*   cursor = (int*)  alloc((size_t)N*4);
  int*   csr    = (int*)  alloc((size_t)E*4);
  unsigned short* bth = (unsigned short*)alloc(131072*2);
  unsigned short* btl = (unsigned short*)alloc(131072*2);
  float* h8     = (float*)alloc((size_t)N*8*4);
  float* bsum   = (float*)alloc(1024);           // contiguous with bsq
  float* bsq    = (float*)alloc(1024);
  float* bnsc   = (float*)alloc(1024);
  float* bnsh   = (float*)alloc(1024);
  unsigned short* Pb = (unsigned short*)alloc((size_t)N*512*2); // bf16 h pre-agg
  float* D      = (float*)alloc((size_t)N*16*4);                // fp32 dots
  float* Q      = (float*)alloc((size_t)N*512*4);               // post-agg fp32
  unsigned short* Qb = (unsigned short*)alloc((size_t)N*512*2); // conv31 out bf16
  (void)ws_size;

  // ---- CSR build ----
  hipMemsetAsync(deg, 0, (size_t)N*4, stream);
  int eb = (E+255)/256;
  k_deg <<<eb, 256, 0, stream>>>(ei+E, deg, E);
  k_scan<<<1, 1024, 0, stream>>>(deg, off, cursor, N);
  k_fill<<<eb, 256, 0, stream>>>(ei, ei+E, cursor, csr, E);

  int mb = (N+63)/64;
  int nb4 = (N+3)/4;
  float invN = 1.0f/(float)N;

  // ---- conv11: 3 -> 64, relu ----
  k_prepB<<<(64*64)/256, 256, 0, stream>>>(W11, bth, btl, 3, 6, 64);
  gemm_mfma<64,0><<<mb, 256, 0, stream>>>(x, bth, btl, nullptr, nullptr,
                                          as11, ad11, Pb, D, N, 3);
  k_agg<64,1,0><<<nb4, 256, 0, stream>>>(Pb, D, off, csr, b11, Q, N);

  // ---- conv12: 64 -> 64, BN stats (apply fused into conv21 staging) ----
  k_prepB<<<(64*64)/256, 256, 0, stream>>>(W12, bth, btl, 64, 6, 64);
  gemm_mfma<64,0><<<mb, 256, 0, stream>>>(Q, bth, btl, nullptr, nullptr,
                                          as12, ad12, Pb, D, N, 64);
  k_agg<64,0,0><<<nb4, 256, 0, stream>>>(Pb, D, off, csr, b12, Q, N);
  hipMemsetAsync(bsum, 0, 2048, stream);
  k_bn_stats<<<512, 64, 0, stream>>>(Q, bsum, bsq, N, 64);
  k_bn_coef<<<1, 64, 0, stream>>>(bsum, bsq, g1, be1, bnsc, bnsh, invN, 64);

  // ---- conv21: 64 -> 256 (BN+lrelu fused in staging), relu out ----
  k_prepB<<<(256*64)/256, 256, 0, stream>>>(W21, bth, btl, 64, 6, 256);
  gemm_mfma<256,1><<<mb, 512, 0, stream>>>(Q, bth, btl, bnsc, bnsh,
                                           as21, ad21, Pb, D, N, 64);
  k_agg<256,1,0><<<nb4, 256, 0, stream>>>(Pb, D, off, csr, b21, Q, N);

  // ---- conv22: 256 -> 256, BN stats ----
  k_prepB<<<(256*256)/256, 256, 0, stream>>>(W22, bth, btl, 256, 8, 256);
  gemm_mfma<256,0><<<mb, 512, 0, stream>>>(Q, bth, btl, nullptr, nullptr,
                                           as22, ad22, Pb, D, N, 256);
  k_agg<256,0,0><<<nb4, 256, 0, stream>>>(Pb, D, off, csr, b22, Q, N);
  hipMemsetAsync(bsum, 0, 2048, stream);
  k_bn_stats<<<512, 256, 0, stream>>>(Q, bsum, bsq, N, 256);
  k_bn_coef<<<1, 256, 0, stream>>>(bsum, bsq, g2, be2, bnsc, bnsh, invN, 256);

  // ---- conv31: 256 -> 512 (BN+lrelu fused), relu out -> bf16 Qb ----
  k_prepB<<<(512*256)/256, 256, 0, stream>>>(W31, bth, btl, 256, 8, 512);
  gemm_mfma<512,1><<<mb, 512, 0, stream>>>(Q, bth, btl, bnsc, bnsh,
                                           as31, ad31, Pb, D, N, 256);
  k_agg<512,1,1><<<nb4, 256, 0, stream>>>(Pb, D, off, csr, b31, Qb, N);

  // ---- conv32: 512 -> 8x1, concat=False, mean, sigmoid ----
  gemm8<<<1024, 256, 0, stream>>>(Qb, W32, h8, N);
  k_final<<<nb4, 256, 0, stream>>>(h8, as32, ad32, off, csr, b32,
                                   (float*)d_out, N);
}

// Round 5
// 1140.378 us; speedup vs baseline: 1.5774x; 1.0048x over previous
//
#include <hip/hip_runtime.h>
#include <math.h>

typedef short short8 __attribute__((ext_vector_type(8)));
typedef short short4v __attribute__((ext_vector_type(4)));
typedef float f32x4 __attribute__((ext_vector_type(4)));

__device__ __forceinline__ unsigned short f2bf(float v){
  unsigned u = __builtin_bit_cast(unsigned, v);
  u += 0x7FFFu + ((u >> 16) & 1u);
  return (unsigned short)(u >> 16);
}
__device__ __forceinline__ float bf2f(unsigned short b){
  unsigned u = ((unsigned)b) << 16;
  return __builtin_bit_cast(float, u);
}

// ---------------------------------------------------------------------------
// CSR build (by dst)
// ---------------------------------------------------------------------------
__global__ void k_deg(const int* __restrict__ dstv, int* __restrict__ deg, int E){
  int e = blockIdx.x*blockDim.x + threadIdx.x;
  if (e < E) atomicAdd(&deg[dstv[e]], 1);
}

__global__ void k_scan(const int* __restrict__ deg, int* __restrict__ off,
                       int* __restrict__ cursor, int N){
  __shared__ int wpre[16];
  __shared__ int s_tot;
  __shared__ int carry;
  int tid = threadIdx.x;
  int lane = tid & 63, wv = tid >> 6;
  if (tid == 0) carry = 0;
  __syncthreads();
  for (int base = 0; base < N; base += 1024){
    int i = base + tid;
    int v = (i < N) ? deg[i] : 0;
    int incl = v;
    #pragma unroll
    for (int d = 1; d < 64; d <<= 1){
      int t = __shfl_up(incl, d, 64);
      if (lane >= d) incl += t;
    }
    if (lane == 63) wpre[wv] = incl;
    __syncthreads();
    if (tid < 16){
      int x = wpre[tid];
      int ix = x;
      #pragma unroll
      for (int d = 1; d < 16; d <<= 1){
        int t = __shfl_up(ix, d, 16);
        if (tid >= d) ix += t;
      }
      wpre[tid] = ix - x;
      if (tid == 15) s_tot = ix;
    }
    __syncthreads();
    int c = carry;
    int excl = c + wpre[wv] + (incl - v);
    if (i < N){ off[i+1] = excl + v; cursor[i] = excl; }
    __syncthreads();
    if (tid == 0) carry = c + s_tot;
    __syncthreads();
  }
  if (tid == 0) off[0] = 0;
}

__global__ void k_fill(const int* __restrict__ srcv, const int* __restrict__ dstv,
                       int* __restrict__ cursor, int* __restrict__ csr, int E){
  int e = blockIdx.x*blockDim.x + threadIdx.x;
  if (e < E){
    int d = dstv[e];
    int p = atomicAdd(&cursor[d], 1);
    csr[p] = srcv[e];
  }
}

// ---------------------------------------------------------------------------
// B pre-convert: W fp32 [K, Nn] -> Bt_hi/Bt_lo bf16 [Nn][Kp]
// ---------------------------------------------------------------------------
__global__ void k_prepB(const float* __restrict__ W, unsigned short* __restrict__ bh,
                        unsigned short* __restrict__ bl, int K, int kpshift, int Nn){
  int Kp = 1 << kpshift;
  int i = blockIdx.x*blockDim.x + threadIdx.x;
  if (i >= Nn*Kp) return;
  int n = i >> kpshift, k = i & (Kp-1);
  float v = (k < K) ? W[(size_t)k*Nn + n] : 0.0f;
  unsigned short h = f2bf(v);
  bh[i] = h;
  bl[i] = f2bf(v - bf2f(h));
}

// ---------------------------------------------------------------------------
// BN coef
// ---------------------------------------------------------------------------
__global__ void k_bn_coef(const float* __restrict__ bsum, const float* __restrict__ bsq,
                          const float* __restrict__ g, const float* __restrict__ b,
                          float* __restrict__ sc, float* __restrict__ sh,
                          float invN, int HC){
  int f = threadIdx.x + blockIdx.x*blockDim.x;
  if (f >= HC) return;
  float mu  = bsum[f]*invN;
  float var = bsq[f]*invN - mu*mu;
  float rs  = rsqrtf(var + 1e-5f) * g[f];
  sc[f] = rs;
  sh[f] = b[f] - mu*rs;
}

// ---------------------------------------------------------------------------
// MFMA GEMM. BM=64, BN = full width.
// AFMT 0: A fp32, 3-term hi/lo (conv11).
// AFMT 1: A bf16 + fused BN affine + lrelu(0.1), 3-term hi/lo (conv21/31).
// AFMT 2: A bf16 exact, 2-term (conv12/22).
// Epilogue: h -> bf16 Pb (stride BN); attention dots -> fp32 Ds/Dd [N][8].
// ---------------------------------------------------------------------------
template<int BN, int AFMT>
__global__ __launch_bounds__((BN==64)?256:512)
void gemm_mfma(const void* __restrict__ Av, const unsigned short* __restrict__ Bh,
               const unsigned short* __restrict__ Bl,
               const float* __restrict__ bnsc, const float* __restrict__ bnsh,
               const float* __restrict__ a_s, const float* __restrict__ a_d,
               unsigned short* __restrict__ Pb, float* __restrict__ Ds,
               float* __restrict__ Dd, int M, int K){
  constexpr int WAVES   = (BN==64) ? 4 : 8;
  constexpr int BLOCK   = WAVES*64;
  constexpr int WAVES_N = BN/64;
  constexpr int WAVES_M = WAVES/WAVES_N;
  constexpr int WM      = 64/WAVES_M;
  constexpr int MF      = WM/16;
  constexpr int CH      = (BN==512)?64 : (BN==256)?32 : 8;
  constexpr int TERMS   = (AFMT==2) ? 2 : 3;
  const int Kp = (K + 63) & ~(int)63;

  __shared__ char lds[(TERMS==3)?16384:8192];

  int tid  = threadIdx.x;
  int lane = tid & 63;
  int wid  = tid >> 6;
  int wn = wid % WAVES_N;
  int wm = wid / WAVES_N;
  int n0w = wn*64;
  int wm0 = wm*WM;
  int m0 = blockIdx.x * 64;

  f32x4 acc[MF][4];
  #pragma unroll
  for (int i = 0; i < MF; ++i)
    #pragma unroll
    for (int j = 0; j < 4; ++j)
      acc[i][j] = (f32x4){0.f,0.f,0.f,0.f};

  constexpr int SITER = 512/BLOCK;

  for (int k0 = 0; k0 < Kp; k0 += 64){
    __syncthreads();
    #pragma unroll
    for (int it = 0; it < SITER; ++it){
      int i = it*BLOCK + tid;
      int row = i >> 3, c8 = i & 7;
      int gm = m0 + row;
      int gk = k0 + c8*8;
      int off = row*128 + ((c8 ^ (row&7))<<4);
      if constexpr (AFMT == 2){
        short8 hv = {0,0,0,0,0,0,0,0};
        if (gm < M) hv = *(const short8*)((const unsigned short*)Av + (size_t)gm*K + gk);
        *(short8*)(lds + off) = hv;
      } else if constexpr (AFMT == 1){
        short8 raw = {0,0,0,0,0,0,0,0};
        if (gm < M) raw = *(const short8*)((const unsigned short*)Av + (size_t)gm*K + gk);
        short8 hi, lo;
        #pragma unroll
        for (int j=0;j<8;++j){
          float u = bf2f((unsigned short)raw[j])*bnsc[gk+j] + bnsh[gk+j];
          u = u > 0.f ? u : 0.1f*u;
          if (gm >= M) u = 0.f;
          unsigned short hb = f2bf(u);
          hi[j] = (short)hb;
          lo[j] = (short)f2bf(u - bf2f(hb));
        }
        *(short8*)(lds + off) = hi;
        *(short8*)(lds + 8192 + off) = lo;
      } else {
        const float* A = (const float*)Av;
        float v[8];
        if (gm < M && gk + 8 <= K){
          const float* ap = A + (size_t)gm*K + gk;
          float4 x0 = *(const float4*)ap;
          float4 x1 = *(const float4*)(ap+4);
          v[0]=x0.x; v[1]=x0.y; v[2]=x0.z; v[3]=x0.w;
          v[4]=x1.x; v[5]=x1.y; v[6]=x1.z; v[7]=x1.w;
        } else {
          #pragma unroll
          for (int j=0;j<8;++j){
            int gkj = gk + j;
            v[j] = (gm < M && gkj < K) ? A[(size_t)gm*K + gkj] : 0.0f;
          }
        }
        short8 hi, lo;
        #pragma unroll
        for (int j=0;j<8;++j){
          unsigned short hb = f2bf(v[j]);
          hi[j] = (short)hb;
          lo[j] = (short)f2bf(v[j] - bf2f(hb));
        }
        *(short8*)(lds + off) = hi;
        *(short8*)(lds + 8192 + off) = lo;
      }
    }
    __syncthreads();
    #pragma unroll
    for (int kk = 0; kk < 2; ++kk){
      short8 bhf[4], blf[4];
      #pragma unroll
      for (int nf = 0; nf < 4; ++nf){
        int ncol = n0w + nf*16 + (lane & 15);
        int kidx = k0 + kk*32 + ((lane>>4)<<3);
        size_t bo = (size_t)ncol*Kp + kidx;
        bhf[nf] = *(const short8*)(Bh + bo);
        blf[nf] = *(const short8*)(Bl + bo);
      }
      #pragma unroll
      for (int mt = 0; mt < MF; ++mt){
        int row = wm0 + mt*16 + (lane & 15);
        int c8 = kk*4 + (lane>>4);
        int off = row*128 + ((c8 ^ (row&7))<<4);
        short8 ah = *(const short8*)(lds + off);
        #pragma unroll
        for (int nf = 0; nf < 4; ++nf){
          acc[mt][nf] = __builtin_amdgcn_mfma_f32_16x16x32_bf16(ah, bhf[nf], acc[mt][nf], 0,0,0);
          acc[mt][nf] = __builtin_amdgcn_mfma_f32_16x16x32_bf16(ah, blf[nf], acc[mt][nf], 0,0,0);
        }
        if constexpr (TERMS == 3){
          short8 al = *(const short8*)(lds + 8192 + off);
          #pragma unroll
          for (int nf = 0; nf < 4; ++nf)
            acc[mt][nf] = __builtin_amdgcn_mfma_f32_16x16x32_bf16(al, bhf[nf], acc[mt][nf], 0,0,0);
        }
      }
    }
  }

  float asv[4], adv[4];
  #pragma unroll
  for (int nf=0; nf<4; ++nf){
    int gcol = n0w + nf*16 + (lane&15);
    asv[nf] = a_s[gcol];
    adv[nf] = a_d[gcol];
  }
  #pragma unroll
  for (int mt = 0; mt < MF; ++mt){
    #pragma unroll
    for (int r = 0; r < 4; ++r){
      int gm = m0 + wm0 + mt*16 + ((lane>>4)<<2) + r;
      bool ok = gm < M;
      #pragma unroll
      for (int nf=0;nf<4;++nf){
        if (ok) Pb[(size_t)gm*BN + n0w + nf*16 + (lane&15)] = f2bf(acc[mt][nf][r]);
      }
      if constexpr (CH == 64){
        float ps = acc[mt][0][r]*asv[0] + acc[mt][1][r]*asv[1]
                 + acc[mt][2][r]*asv[2] + acc[mt][3][r]*asv[3];
        float pd = acc[mt][0][r]*adv[0] + acc[mt][1][r]*adv[1]
                 + acc[mt][2][r]*adv[2] + acc[mt][3][r]*adv[3];
        #pragma unroll
        for (int d2=1; d2<16; d2<<=1){ ps += __shfl_xor(ps,d2,64); pd += __shfl_xor(pd,d2,64); }
        if (ok && (lane&15)==0){
          int head = n0w >> 6;
          Ds[(size_t)gm*8 + head] = ps;
          Dd[(size_t)gm*8 + head] = pd;
        }
      } else if constexpr (CH == 32){
        float ps0 = acc[mt][0][r]*asv[0] + acc[mt][1][r]*asv[1];
        float ps1 = acc[mt][2][r]*asv[2] + acc[mt][3][r]*asv[3];
        float pd0 = acc[mt][0][r]*adv[0] + acc[mt][1][r]*adv[1];
        float pd1 = acc[mt][2][r]*adv[2] + acc[mt][3][r]*adv[3];
        #pragma unroll
        for (int d2=1; d2<16; d2<<=1){
          ps0 += __shfl_xor(ps0,d2,64); ps1 += __shfl_xor(ps1,d2,64);
          pd0 += __shfl_xor(pd0,d2,64); pd1 += __shfl_xor(pd1,d2,64);
        }
        if (ok && (lane&15)==0){
          int head = n0w >> 5;
          Ds[(size_t)gm*8 + head]     = ps0;
          Ds[(size_t)gm*8 + head + 1] = ps1;
          Dd[(size_t)gm*8 + head]     = pd0;
          Dd[(size_t)gm*8 + head + 1] = pd1;
        }
      } else {
        #pragma unroll
        for (int nf=0;nf<4;++nf){
          float ps = acc[mt][nf][r]*asv[nf];
          float pd = acc[mt][nf][r]*adv[nf];
          #pragma unroll
          for (int d2=1; d2<8; d2<<=1){ ps += __shfl_xor(ps,d2,64); pd += __shfl_xor(pd,d2,64); }
          if (ok && (lane&7)==0){
            int head = nf*2 + ((lane>>3)&1);
            Ds[(size_t)gm*8 + head] = ps;
            Dd[(size_t)gm*8 + head] = pd;
          }
        }
      }
    }
  }
}

// ---------------------------------------------------------------------------
// aggregation: bf16 h (Pb, stride HC) + fp32 dots Ds/Dd [N][8].
// Output always bf16. Fast path deg<64; generic slow path.
// ---------------------------------------------------------------------------
template<int HC, int ACT>
__global__ __launch_bounds__(256)
void k_agg(const unsigned short* __restrict__ Pb, const float* __restrict__ Ds,
           const float* __restrict__ Dd, const int* __restrict__ off,
           const int* __restrict__ csr, const float* __restrict__ bias,
           unsigned short* __restrict__ outb, int N){
  constexpr int R = HC/64;
  __shared__ float salpha[4][512];
  int lane = threadIdx.x & 63;
  int wid  = threadIdx.x >> 6;
  int n = blockIdx.x*4 + wid;
  if (n >= N) return;
  int o0 = off[n], deg = off[n+1]-o0;
  int myh = lane >> 3;

  float aldn[8];
  {
    const float* dn = Dd + (size_t)n*8;
    float4 x0 = *(const float4*)dn;
    float4 x1 = *(const float4*)(dn+4);
    aldn[0]=x0.x; aldn[1]=x0.y; aldn[2]=x0.z; aldn[3]=x0.w;
    aldn[4]=x1.x; aldn[5]=x1.y; aldn[6]=x1.z; aldn[7]=x1.w;
  }

  float acc[R];
  #pragma unroll
  for (int j=0;j<R;++j) acc[j]=0.f;

  if (deg < 64){
    int nE = deg + 1;
    int myidx = (lane < deg) ? csr[o0+lane] : n;
    bool active = (lane < nE);
    float v[8];
    {
      const float* dp = Ds + (size_t)myidx*8;
      float4 x0 = *(const float4*)dp;
      float4 x1 = *(const float4*)(dp+4);
      float t[8] = {x0.x,x0.y,x0.z,x0.w,x1.x,x1.y,x1.z,x1.w};
      #pragma unroll
      for (int h=0;h<8;++h){
        float u = t[h] + aldn[h];
        u = u > 0.f ? u : 0.2f*u;
        v[h] = active ? u : -1e30f;
      }
    }
    float m[8];
    #pragma unroll
    for (int h=0;h<8;++h) m[h]=v[h];
    #pragma unroll
    for (int d=1; d<64; d<<=1)
      #pragma unroll
      for (int h=0;h<8;++h) m[h] = fmaxf(m[h], __shfl_xor(m[h], d, 64));
    float sv[8], s[8];
    #pragma unroll
    for (int h=0;h<8;++h){ sv[h] = active ? __expf(v[h]-m[h]) : 0.f; s[h]=sv[h]; }
    #pragma unroll
    for (int d=1; d<64; d<<=1)
      #pragma unroll
      for (int h=0;h<8;++h) s[h] += __shfl_xor(s[h], d, 64);
    if (active){
      #pragma unroll
      for (int h=0;h<8;++h) salpha[wid][lane*8+h] = sv[h] / (s[h] + 1e-16f);
    }
    asm volatile("s_waitcnt lgkmcnt(0)" ::: "memory");

    for (int e=0; e<nE; ++e){
      int src = __shfl(myidx, e, 64);
      float alpha = salpha[wid][e*8 + myh];
      const unsigned short* hp = Pb + (size_t)src*HC + lane*R;
      if constexpr (R == 1){
        acc[0] += alpha * bf2f(hp[0]);
      } else if constexpr (R == 4){
        short4v w = *(const short4v*)hp;
        #pragma unroll
        for (int j=0;j<4;++j) acc[j] += alpha * bf2f((unsigned short)w[j]);
      } else {
        short8 w = *(const short8*)hp;
        #pragma unroll
        for (int j=0;j<8;++j) acc[j] += alpha * bf2f((unsigned short)w[j]);
      }
    }
  } else {
    float m[8];
    #pragma unroll
    for (int h=0;h<8;++h) m[h] = -1e30f;
    for (int e = lane; e <= deg; e += 64){
      int src = (e < deg) ? csr[o0+e] : n;
      const float* ap = Ds + (size_t)src*8;
      #pragma unroll
      for (int h=0;h<8;++h){
        float u = ap[h] + aldn[h];
        u = u > 0.f ? u : 0.2f*u;
        m[h] = fmaxf(m[h], u);
      }
    }
    #pragma unroll
    for (int d=1; d<64; d<<=1)
      #pragma unroll
      for (int h=0;h<8;++h) m[h] = fmaxf(m[h], __shfl_xor(m[h], d, 64));
    float s[8] = {0,0,0,0,0,0,0,0};
    for (int e = lane; e <= deg; e += 64){
      int src = (e < deg) ? csr[o0+e] : n;
      const float* ap = Ds + (size_t)src*8;
      #pragma unroll
      for (int h=0;h<8;++h){
        float u = ap[h] + aldn[h];
        u = u > 0.f ? u : 0.2f*u;
        s[h] += __expf(u - m[h]);
      }
    }
    #pragma unroll
    for (int d=1; d<64; d<<=1)
      #pragma unroll
      for (int h=0;h<8;++h) s[h] += __shfl_xor(s[h], d, 64);
    float mh = m[myh];
    float rsh = 1.0f/(s[myh] + 1e-16f);
    float adh = aldn[myh];
    for (int e = 0; e <= deg; ++e){
      int src = (e < deg) ? csr[o0+e] : n;
      float u = Ds[(size_t)src*8 + myh] + adh;
      u = u > 0.f ? u : 0.2f*u;
      float alpha = __expf(u - mh) * rsh;
      const unsigned short* hp = Pb + (size_t)src*HC + lane*R;
      if constexpr (R == 1){
        acc[0] += alpha * bf2f(hp[0]);
      } else if constexpr (R == 4){
        short4v w = *(const short4v*)hp;
        #pragma unroll
        for (int j=0;j<4;++j) acc[j] += alpha * bf2f((unsigned short)w[j]);
      } else {
        short8 w = *(const short8*)hp;
        #pragma unroll
        for (int j=0;j<8;++j) acc[j] += alpha * bf2f((unsigned short)w[j]);
      }
    }
  }

  #pragma unroll
  for (int j = 0; j < R; ++j){
    int f = lane*R + j;
    float v = acc[j] + bias[f];
    if (ACT == 1) v = fmaxf(v, 0.0f);
    outb[(size_t)n*HC + f] = f2bf(v);
  }
}

// ---------------------------------------------------------------------------
// BatchNorm stats over bf16 activations
// ---------------------------------------------------------------------------
__global__ void k_bn_stats(const unsigned short* __restrict__ x, float* __restrict__ gsum,
                           float* __restrict__ gsq, int N, int HC){
  int f = threadIdx.x;
  float s = 0.f, q = 0.f;
  for (int r = blockIdx.x; r < N; r += gridDim.x){
    float v = bf2f(x[(size_t)r*HC + f]);
    s += v; q += v*v;
  }
  atomicAdd(&gsum[f], s);
  atomicAdd(&gsq[f], q);
}

// ---------------------------------------------------------------------------
// conv32 GEMM: bf16 A [M,512] x fp32 W [512,8] -> fp32 h8 [M,8]
// ---------------------------------------------------------------------------
__global__ __launch_bounds__(256)
void gemm8(const unsigned short* __restrict__ Qb, const float* __restrict__ W,
           float* __restrict__ h8, int M){
  int lane = threadIdx.x & 63;
  int gw = (blockIdx.x*blockDim.x + threadIdx.x) >> 6;
  int nw = (gridDim.x*blockDim.x) >> 6;
  float w[8][8];
  const float* wp = W + lane*64;
  #pragma unroll
  for (int j=0;j<8;++j){
    float4 a = *(const float4*)(wp + j*8);
    float4 b = *(const float4*)(wp + j*8 + 4);
    w[j][0]=a.x; w[j][1]=a.y; w[j][2]=a.z; w[j][3]=a.w;
    w[j][4]=b.x; w[j][5]=b.y; w[j][6]=b.z; w[j][7]=b.w;
  }
  for (int n = gw; n < M; n += nw){
    short8 v8 = *(const short8*)(Qb + (size_t)n*512 + lane*8);
    float p[8] = {0,0,0,0,0,0,0,0};
    #pragma unroll
    for (int j=0;j<8;++j){
      float x = bf2f((unsigned short)v8[j]);
      #pragma unroll
      for (int o=0;o<8;++o) p[o] += x * w[j][o];
    }
    #pragma unroll
    for (int d=1; d<64; d<<=1)
      #pragma unroll
      for (int o=0;o<8;++o) p[o] += __shfl_xor(p[o], d, 64);
    if (lane == 0){
      float4 y0 = make_float4(p[0],p[1],p[2],p[3]);
      float4 y1 = make_float4(p[4],p[5],p[6],p[7]);
      *(float4*)(h8 + (size_t)n*8)     = y0;
      *(float4*)(h8 + (size_t)n*8 + 4) = y1;
    }
  }
}

// ---------------------------------------------------------------------------
// final conv: wave-per-node
// ---------------------------------------------------------------------------
__global__ __launch_bounds__(256)
void k_final(const float* __restrict__ h8, const float* __restrict__ a_s,
             const float* __restrict__ a_d, const int* __restrict__ off,
             const int* __restrict__ csr, const float* __restrict__ b32,
             float* __restrict__ outp, int N){
  int lane = threadIdx.x & 63;
  int wv   = threadIdx.x >> 6;
  int n = blockIdx.x*4 + wv;
  if (n >= N) return;
  int o0 = off[n], deg = off[n+1]-o0;
  float asv[8], adv[8];
  #pragma unroll
  for (int h=0;h<8;++h){ asv[h]=a_s[h]; adv[h]=a_d[h]; }
  float aldn[8];
  {
    const float* hp = h8 + (size_t)n*8;
    float4 x0 = *(const float4*)hp;
    float4 x1 = *(const float4*)(hp+4);
    float hn[8] = {x0.x,x0.y,x0.z,x0.w,x1.x,x1.y,x1.z,x1.w};
    #pragma unroll
    for (int h=0;h<8;++h) aldn[h] = hn[h]*adv[h];
  }

  if (deg < 64){
    int nE = deg + 1;
    int src = (lane < deg) ? csr[o0+lane] : n;
    bool act = (lane < nE);
    float hs[8];
    {
      const float* hp = h8 + (size_t)src*8;
      float4 x0 = *(const float4*)hp;
      float4 x1 = *(const float4*)(hp+4);
      hs[0]=x0.x; hs[1]=x0.y; hs[2]=x0.z; hs[3]=x0.w;
      hs[4]=x1.x; hs[5]=x1.y; hs[6]=x1.z; hs[7]=x1.w;
    }
    float v[8];
    #pragma unroll
    for (int h=0;h<8;++h){
      float u = hs[h]*asv[h] + aldn[h];
      u = u > 0.f ? u : 0.2f*u;
      v[h] = act ? u : -1e30f;
    }
    float m[8];
    #pragma unroll
    for (int h=0;h<8;++h) m[h]=v[h];
    #pragma unroll
    for (int d=1; d<64; d<<=1)
      #pragma unroll
      for (int h=0;h<8;++h) m[h] = fmaxf(m[h], __shfl_xor(m[h], d, 64));
    float s[8], t[8];
    #pragma unroll
    for (int h=0;h<8;++h){
      float e = act ? __expf(v[h]-m[h]) : 0.f;
      s[h]=e; t[h]=e*hs[h];
    }
    #pragma unroll
    for (int d=1; d<64; d<<=1)
      #pragma unroll
      for (int h=0;h<8;++h){
        s[h] += __shfl_xor(s[h], d, 64);
        t[h] += __shfl_xor(t[h], d, 64);
      }
    if (lane == 0){
      float o = 0.f;
      #pragma unroll
      for (int h=0;h<8;++h) o += t[h]/(s[h]+1e-16f);
      o = o*0.125f + b32[0];
      outp[n] = 1.0f/(1.0f + __expf(-o));
    }
  } else if (lane == 0){
    float m[8], s[8], agg[8];
    #pragma unroll
    for (int h=0;h<8;++h){ m[h]=-1e30f; s[h]=0.f; agg[h]=0.f; }
    for (int e = 0; e <= deg; ++e){
      int src = (e < deg) ? csr[o0+e] : n;
      #pragma unroll
      for (int h=0;h<8;++h){
        float u = h8[(size_t)src*8+h]*asv[h] + aldn[h];
        u = u > 0.f ? u : 0.2f*u;
        m[h] = fmaxf(m[h], u);
      }
    }
    for (int e = 0; e <= deg; ++e){
      int src = (e < deg) ? csr[o0+e] : n;
      #pragma unroll
      for (int h=0;h<8;++h){
        float u = h8[(size_t)src*8+h]*asv[h] + aldn[h];
        u = u > 0.f ? u : 0.2f*u;
        float ex = __expf(u - m[h]);
        s[h] += ex;
        agg[h] += ex * h8[(size_t)src*8+h];
      }
    }
    float o = 0.f;
    #pragma unroll
    for (int h=0;h<8;++h) o += agg[h]/(s[h]+1e-16f);
    o = o*0.125f + b32[0];
    outp[n] = 1.0f/(1.0f + __expf(-o));
  }
}

// ---------------------------------------------------------------------------
extern "C" void kernel_launch(void* const* d_in, const int* in_sizes, int n_in,
                              void* d_out, int out_size, void* d_ws, size_t ws_size,
                              hipStream_t stream){
  int N = in_sizes[0]/3;
  int E = in_sizes[1]/2;
  const float* x    = (const float*)d_in[0];
  const int*   ei   = (const int*)  d_in[1];
  const float* W11  = (const float*)d_in[2];
  const float* as11 = (const float*)d_in[3];
  const float* ad11 = (const float*)d_in[4];
  const float* b11  = (const float*)d_in[5];
  const float* W12  = (const float*)d_in[6];
  const float* as12 = (const float*)d_in[7];
  const float* ad12 = (const float*)d_in[8];
  const float* b12  = (const float*)d_in[9];
  const float* g1   = (const float*)d_in[10];
  const float* be1  = (const float*)d_in[11];
  const float* W21  = (const float*)d_in[12];
  const float* as21 = (const float*)d_in[13];
  const float* ad21 = (const float*)d_in[14];
  const float* b21  = (const float*)d_in[15];
  const float* W22  = (const float*)d_in[16];
  const float* as22 = (const float*)d_in[17];
  const float* ad22 = (const float*)d_in[18];
  const float* b22  = (const float*)d_in[19];
  const float* g2   = (const float*)d_in[20];
  const float* be2  = (const float*)d_in[21];
  const float* W31  = (const float*)d_in[22];
  const float* as31 = (const float*)d_in[23];
  const float* ad31 = (const float*)d_in[24];
  const float* b31  = (const float*)d_in[25];
  const float* W32  = (const float*)d_in[26];
  const float* as32 = (const float*)d_in[27];
  const float* ad32 = (const float*)d_in[28];
  const float* b32  = (const float*)d_in[29];

  char* ws = (char*)d_ws;
  size_t o = 0;
  auto alloc = [&](size_t bytes)->char*{
    char* p = ws + o;
    o = (o + bytes + 255) & ~(size_t)255;
    return p;
  };
  int*   deg    = (int*)  alloc((size_t)N*4);
  int*   off    = (int*)  alloc((size_t)(N+1)*4);
  int*   cursor = (int*)  alloc((size_t)N*4);
  int*   csr    = (int*)  alloc((size_t)E*4);
  unsigned short* bth = (unsigned short*)alloc(131072*2);
  unsigned short* btl = (unsigned short*)alloc(131072*2);
  float* h8     = (float*)alloc((size_t)N*8*4);
  float* bsum   = (float*)alloc(1024);
  float* bsq    = (float*)alloc(1024);
  float* bnsc   = (float*)alloc(1024);
  float* bnsh   = (float*)alloc(1024);
  unsigned short* Pb = (unsigned short*)alloc((size_t)N*512*2); // bf16 pre-agg h
  unsigned short* Qb = (unsigned short*)alloc((size_t)N*512*2); // bf16 activations
  float* Dsb    = (float*)alloc((size_t)N*8*4);                 // als dots
  float* Ddb    = (float*)alloc((size_t)N*8*4);                 // ald dots
  (void)ws_size;

  // ---- CSR build ----
  hipMemsetAsync(deg, 0, (size_t)N*4, stream);
  int eb = (E+255)/256;
  k_deg <<<eb, 256, 0, stream>>>(ei+E, deg, E);
  k_scan<<<1, 1024, 0, stream>>>(deg, off, cursor, N);
  k_fill<<<eb, 256, 0, stream>>>(ei, ei+E, cursor, csr, E);

  int mb = (N+63)/64;
  int nb4 = (N+3)/4;
  float invN = 1.0f/(float)N;

  // ---- conv11: 3 -> 64 (A fp32, 3-term), relu ----
  k_prepB<<<(64*64)/256, 256, 0, stream>>>(W11, bth, btl, 3, 6, 64);
  gemm_mfma<64,0><<<mb, 256, 0, stream>>>(x, bth, btl, nullptr, nullptr,
                                          as11, ad11, Pb, Dsb, Ddb, N, 3);
  k_agg<64,1><<<nb4, 256, 0, stream>>>(Pb, Dsb, Ddb, off, csr, b11, Qb, N);

  // ---- conv12: 64 -> 64 (A bf16 exact, 2-term), BN stats after ----
  k_prepB<<<(64*64)/256, 256, 0, stream>>>(W12, bth, btl, 64, 6, 64);
  gemm_mfma<64,2><<<mb, 256, 0, stream>>>(Qb, bth, btl, nullptr, nullptr,
                                          as12, ad12, Pb, Dsb, Ddb, N, 64);
  k_agg<64,0><<<nb4, 256, 0, stream>>>(Pb, Dsb, Ddb, off, csr, b12, Qb, N);
  hipMemsetAsync(bsum, 0, 2048, stream);
  k_bn_stats<<<512, 64, 0, stream>>>(Qb, bsum, bsq, N, 64);
  k_bn_coef<<<1, 64, 0, stream>>>(bsum, bsq, g1, be1, bnsc, bnsh, invN, 64);

  // ---- conv21: 64 -> 256 (BN+lrelu fused, 3-term), relu out ----
  k_prepB<<<(256*64)/256, 256, 0, stream>>>(W21, bth, btl, 64, 6, 256);
  gemm_mfma<256,1><<<mb, 512, 0, stream>>>(Qb, bth, btl, bnsc, bnsh,
                                           as21, ad21, Pb, Dsb, Ddb, N, 64);
  k_agg<256,1><<<nb4, 256, 0, stream>>>(Pb, Dsb, Ddb, off, csr, b21, Qb, N);

  // ---- conv22: 256 -> 256 (A bf16 exact, 2-term), BN stats ----
  k_prepB<<<(256*256)/256, 256, 0, stream>>>(W22, bth, btl, 256, 8, 256);
  gemm_mfma<256,2><<<mb, 512, 0, stream>>>(Qb, bth, btl, nullptr, nullptr,
                                           as22, ad22, Pb, Dsb, Ddb, N, 256);
  k_agg<256,0><<<nb4, 256, 0, stream>>>(Pb, Dsb, Ddb, off, csr, b22, Qb, N);
  hipMemsetAsync(bsum, 0, 2048, stream);
  k_bn_stats<<<512, 256, 0, stream>>>(Qb, bsum, bsq, N, 256);
  k_bn_coef<<<1, 256, 0, stream>>>(bsum, bsq, g2, be2, bnsc, bnsh, invN, 256);

  // ---- conv31: 256 -> 512 (BN+lrelu fused, 3-term), relu out ----
  k_prepB<<<(512*256)/256, 256, 0, stream>>>(W31, bth, btl, 256, 8, 512);
  gemm_mfma<512,1><<<mb, 512, 0, stream>>>(Qb, bth, btl, bnsc, bnsh,
                                           as31, ad31, Pb, Dsb, Ddb, N, 256);
  k_agg<512,1><<<nb4, 256, 0, stream>>>(Pb, Dsb, Ddb, off, csr, b31, Qb, N);

  // ---- conv32: 512 -> 8x1, concat=False, mean, sigmoid ----
  gemm8<<<1024, 256, 0, stream>>>(Qb, W32, h8, N);
  k_final<<<nb4, 256, 0, stream>>>(h8, as32, ad32, off, csr, b32,
                                   (float*)d_out, N);
}